// Round 9
// baseline (405.633 us; speedup 1.0000x reference)
//
#include <hip/hip_runtime.h>
#include <math.h>

// MMGCN: GEMM pushed through the (linear) aggregation + LDS-free bf16 MFMA GEMMs.
//   z1  = A . (xn*onrm)                      [shared by v,t]   -> conv1 GEMM K=128 (MFMA)
//   zlx = A . leaky(xn*onrm)                 [shared by v,t]   -> conv2 top half
//   zx  = A . leaky(xhat_{v,t}*onrm) interleaved               -> conv2 bottom half
//   out256 = ([zlx | zx] @ B2)*in_norm + 0.5(b1v+b1t) + gid    -> one K=384 GEMM (MFMA)
// GEMM K-loops use an explicit depth-2 register pipeline (fragment-set A/B rotation):
// round-8 showed VGPR=44 => compiler serialized each K-step behind vmcnt(0) (1.3 TB/s,
// latency-bound regardless of occupancy). The rotation keeps ~12 loads in flight.

typedef unsigned int uint;
typedef unsigned short ushort;
using bf16x8 = __attribute__((ext_vector_type(8))) short;
using f32x4  = __attribute__((ext_vector_type(4))) float;

__device__ __forceinline__ float lrelu(float v) { return v >= 0.0f ? v : 0.01f * v; }
__device__ __forceinline__ float bf2f(uint us) { return __uint_as_float(us << 16); }
__device__ __forceinline__ ushort f2bf(float f) {
    uint u = __float_as_uint(f);
    u += 0x7fffu + ((u >> 16) & 1u);   // round-to-nearest-even
    return (ushort)(u >> 16);
}

// ---------------- degree histograms ----------------
__global__ void k_degrees(const int* __restrict__ src, const int* __restrict__ dst,
                          int* __restrict__ deg_out, int* __restrict__ deg_in, int E) {
    int e = blockIdx.x * blockDim.x + threadIdx.x;
    if (e < E) {
        atomicAdd(&deg_out[src[e]], 1);
        atomicAdd(&deg_in[dst[e]], 1);
    }
}

__global__ void k_norms(const int* __restrict__ deg_out, const int* __restrict__ deg_in,
                        float* __restrict__ onrm, float* __restrict__ inrm, int n) {
    int i = blockIdx.x * blockDim.x + threadIdx.x;
    if (i < n) {
        onrm[i] = 1.0f / sqrtf((float)max(deg_out[i], 1));
        inrm[i] = 1.0f / sqrtf((float)max(deg_in[i], 1));
    }
}

// ---------------- multi-block prefix scan: deg_in -> row_ptr ----------------
__global__ void k_scan1(const int* __restrict__ deg, int* __restrict__ row_ptr,
                        int* __restrict__ csum, int n) {
    __shared__ int wsum[16];
    __shared__ int wpre[16];
    int lane = threadIdx.x & 63;
    int wid  = threadIdx.x >> 6;
    int i = blockIdx.x * 1024 + threadIdx.x;
    int v = (i < n) ? deg[i] : 0;
    int s = v;
    #pragma unroll
    for (int off = 1; off < 64; off <<= 1) {
        int t = __shfl_up(s, off, 64);
        if (lane >= off) s += t;
    }
    if (lane == 63) wsum[wid] = s;
    __syncthreads();
    if (wid == 0) {
        int wv = (lane < 16) ? wsum[lane] : 0;
        int ss = wv;
        #pragma unroll
        for (int off = 1; off < 16; off <<= 1) {
            int t = __shfl_up(ss, off, 64);
            if (lane >= off) ss += t;
        }
        if (lane < 16) wpre[lane] = ss - wv;
    }
    __syncthreads();
    int incl = s + wpre[wid];
    if (i < n) row_ptr[i + 1] = incl;                        // chunk-local for now
    if (threadIdx.x == 1023) csum[blockIdx.x] = incl;        // chunk total
}

__global__ void k_scan2(int* __restrict__ csum, int nb) {
    __shared__ int wsum[16];
    __shared__ int wpre[16];
    int lane = threadIdx.x & 63;
    int wid  = threadIdx.x >> 6;
    int i = threadIdx.x;
    int v = (i < nb) ? csum[i] : 0;
    int s = v;
    #pragma unroll
    for (int off = 1; off < 64; off <<= 1) {
        int t = __shfl_up(s, off, 64);
        if (lane >= off) s += t;
    }
    if (lane == 63) wsum[wid] = s;
    __syncthreads();
    if (wid == 0) {
        int wv = (lane < 16) ? wsum[lane] : 0;
        int ss = wv;
        #pragma unroll
        for (int off = 1; off < 16; off <<= 1) {
            int t = __shfl_up(ss, off, 64);
            if (lane >= off) ss += t;
        }
        if (lane < 16) wpre[lane] = ss - wv;
    }
    __syncthreads();
    if (i < nb) csum[i] = s + wpre[wid];
}

__global__ void k_scan3(int* __restrict__ row_ptr, const int* __restrict__ csum, int n) {
    int i = blockIdx.x * blockDim.x + threadIdx.x;
    if (i == 0) row_ptr[0] = 0;
    if (i < n) {
        int b = i >> 10;
        if (b > 0) row_ptr[i + 1] += csum[b - 1];
    }
}

__global__ void k_fill(const int* __restrict__ src, const int* __restrict__ dst,
                       const int* __restrict__ row_ptr, int* __restrict__ cursor,
                       int* __restrict__ col, int E) {
    int e = blockIdx.x * blockDim.x + threadIdx.x;
    if (e < E) {
        int d = dst[e];
        int pos = atomicAdd(&cursor[d], 1);
        col[row_ptr[d] + pos] = src[e];
    }
}

// ---------------- weight prep ----------------
// W1T [256 cols][128 k]: cols 0:128 = Wv0 cols; 128:256 = Wt0 cols  (de-interleaved)
// W2T [128 cols][384 k]: k 0:128 = 0.5(Wv1+Wt1); k 128+2q+b = 0.5 Wb1[128+q]  (interleaved)
__global__ void k_wprep(const float* __restrict__ Wv0, const float* __restrict__ Wt0,
                        const float* __restrict__ Wv1, const float* __restrict__ Wt1,
                        const float* __restrict__ bv0, const float* __restrict__ bt0,
                        const float* __restrict__ bv1, const float* __restrict__ bt1,
                        ushort* __restrict__ W1T, ushort* __restrict__ W2T,
                        float* __restrict__ bias_cat, float* __restrict__ bias2) {
    int t = blockIdx.x * blockDim.x + threadIdx.x;
    if (t < 256 * 128) {
        int c = t >> 7, k = t & 127;
        float v = (c < 128) ? Wv0[k * 128 + c] : Wt0[k * 128 + (c - 128)];
        W1T[c * 128 + k] = f2bf(v);
    }
    if (t < 128 * 384) {
        int c = t / 384, r = t % 384;
        float v;
        if (r < 128) v = 0.5f * (Wv1[r * 128 + c] + Wt1[r * 128 + c]);
        else {
            int q = (r - 128) >> 1;
            v = 0.5f * (((r - 128) & 1) ? Wt1[(128 + q) * 128 + c] : Wv1[(128 + q) * 128 + c]);
        }
        W2T[c * 384 + r] = f2bf(v);
    }
    if (t < 256) bias_cat[t] = (t < 128) ? bv0[t] : bt0[t - 128];
    if (t < 128) bias2[t] = 0.5f * (bv1[t] + bt1[t]);
}

// ------- row L2-normalize x; out[:,0:128]=leaky(xn); xn_sc=xn*onrm (bf16); gid bf16 -------
__global__ void k_normx(const float* __restrict__ x, const float* __restrict__ onrm,
                        const int* __restrict__ dsti, const float* __restrict__ id_emb,
                        ushort* __restrict__ xn_sc, ushort* __restrict__ gid,
                        float* __restrict__ out, int n) {
    int gtid = blockIdx.x * blockDim.x + threadIdx.x;
    int row  = gtid >> 6;
    int lane = gtid & 63;
    if (row >= n) return;
    int c = lane * 2;
    float2 v = *(const float2*)&x[(size_t)row * 128 + c];
    float s = v.x * v.x + v.y * v.y;
    #pragma unroll
    for (int off = 1; off < 64; off <<= 1) s += __shfl_xor(s, off, 64);
    float scale = 1.0f / fmaxf(sqrtf(s), 1e-12f);
    float nx = v.x * scale, ny = v.y * scale;
    *(float2*)&out[(size_t)row * 384 + c] = make_float2(lrelu(nx), lrelu(ny));
    float so = onrm[row];
    uint p = (uint)f2bf(nx * so) | ((uint)f2bf(ny * so) << 16);
    *(uint*)&xn_sc[(size_t)row * 128 + c] = p;
    // densify id_emb[dsti[row]] -> gid[row] (bf16)
    int g = dsti[row];
    float2 ge = *(const float2*)&id_emb[(size_t)g * 128 + c];
    uint pg = (uint)f2bf(ge.x) | ((uint)f2bf(ge.y) << 16);
    *(uint*)&gid[(size_t)row * 128 + c] = pg;
}

// ---------------- gather pass 1: z1 = A.xn_sc ; zlx = A.leaky(xn_sc)  (both bf16) -------
__global__ void k_agg1(const ushort* __restrict__ xn_sc, const int* __restrict__ rp,
                       const int* __restrict__ col, ushort* __restrict__ z1,
                       ushort* __restrict__ zbig, int n) {
    int gtid = blockIdx.x * blockDim.x + threadIdx.x;
    int row  = gtid >> 6;
    int lane = gtid & 63;
    if (row >= n) return;
    int c = lane * 2;
    float zx = 0.f, zy = 0.f, lx = 0.f, ly = 0.f;
    int e0 = rp[row], e1 = rp[row + 1];
    int e = e0;
    for (; e + 1 < e1; e += 2) {
        int s0 = col[e], s1 = col[e + 1];
        uint v0 = *(const uint*)&xn_sc[(size_t)s0 * 128 + c];
        uint v1 = *(const uint*)&xn_sc[(size_t)s1 * 128 + c];
        float ax = bf2f(v0 & 0xffffu), ay = bf2f(v0 >> 16);
        float bx = bf2f(v1 & 0xffffu), by = bf2f(v1 >> 16);
        zx += ax + bx; zy += ay + by;
        lx += lrelu(ax) + lrelu(bx); ly += lrelu(ay) + lrelu(by);
    }
    if (e < e1) {
        uint v0 = *(const uint*)&xn_sc[(size_t)col[e] * 128 + c];
        float ax = bf2f(v0 & 0xffffu), ay = bf2f(v0 >> 16);
        zx += ax; zy += ay; lx += lrelu(ax); ly += lrelu(ay);
    }
    *(uint*)&z1[(size_t)row * 128 + c]  = (uint)f2bf(zx) | ((uint)f2bf(zy) << 16);
    *(uint*)&zbig[(size_t)row * 384 + c] = (uint)f2bf(lx) | ((uint)f2bf(ly) << 16);
}

// ---------------- gather pass 2: zx_inter = A.xhat_sc  (256-wide, bf16) ----------------
__global__ void k_agg2(const ushort* __restrict__ xhat_sc, const int* __restrict__ rp,
                       const int* __restrict__ col, ushort* __restrict__ zbig, int n) {
    int gtid = blockIdx.x * blockDim.x + threadIdx.x;
    int row  = gtid >> 6;
    int lane = gtid & 63;
    if (row >= n) return;
    int c = lane * 4;
    float a0 = 0.f, a1 = 0.f, a2 = 0.f, a3 = 0.f;
    int e0 = rp[row], e1 = rp[row + 1];
    int e = e0;
    for (; e + 1 < e1; e += 2) {
        int s0 = col[e], s1 = col[e + 1];
        uint2 v0 = *(const uint2*)&xhat_sc[(size_t)s0 * 256 + c];
        uint2 v1 = *(const uint2*)&xhat_sc[(size_t)s1 * 256 + c];
        a0 += bf2f(v0.x & 0xffffu) + bf2f(v1.x & 0xffffu);
        a1 += bf2f(v0.x >> 16)     + bf2f(v1.x >> 16);
        a2 += bf2f(v0.y & 0xffffu) + bf2f(v1.y & 0xffffu);
        a3 += bf2f(v0.y >> 16)     + bf2f(v1.y >> 16);
    }
    if (e < e1) {
        uint2 v0 = *(const uint2*)&xhat_sc[(size_t)col[e] * 256 + c];
        a0 += bf2f(v0.x & 0xffffu); a1 += bf2f(v0.x >> 16);
        a2 += bf2f(v0.y & 0xffffu); a3 += bf2f(v0.y >> 16);
    }
    uint2 p;
    p.x = (uint)f2bf(a0) | ((uint)f2bf(a1) << 16);
    p.y = (uint)f2bf(a2) | ((uint)f2bf(a3) << 16);
    *(uint2*)&zbig[(size_t)row * 384 + 128 + c] = p;
}

// ---------------- conv1 MFMA GEMM, LDS-free, depth-2 pipelined: 64r x 256c / block ------
__global__ __launch_bounds__(256) void k_gemm1(
    const ushort* __restrict__ A, const ushort* __restrict__ WT,
    const float* __restrict__ inrm, const float* __restrict__ onrm,
    const ushort* __restrict__ gid, const float* __restrict__ bias,
    ushort* __restrict__ xhat_sc, float* __restrict__ out, int n)
{
    int tid  = threadIdx.x;
    int lane = tid & 63;
    int w    = tid >> 6;
    int wm   = w >> 1, wn = w & 1;
    int row0 = blockIdx.x * 64;
    int lr = lane & 15;
    int lk = lane >> 4;

    f32x4 acc[2][8];
    f32x4 zero = {0.f, 0.f, 0.f, 0.f};
    #pragma unroll
    for (int m = 0; m < 2; m++)
        #pragma unroll
        for (int nn = 0; nn < 8; nn++) acc[m][nn] = zero;

    int rg[2]; bool ok[2];
    #pragma unroll
    for (int m = 0; m < 2; m++) { rg[m] = row0 + wm * 32 + m * 16 + lr; ok[m] = rg[m] < n; }
    bf16x8 zf = {0, 0, 0, 0, 0, 0, 0, 0};

    auto load_frag = [&](int ks, bf16x8* af, bf16x8* bf) {
        int koff = ks * 32 + lk * 8;
        #pragma unroll
        for (int m = 0; m < 2; m++)
            af[m] = ok[m] ? *(const bf16x8*)&A[(size_t)rg[m] * 128 + koff] : zf;
        #pragma unroll
        for (int nn = 0; nn < 4; nn++) {
            int cv = wn * 64 + nn * 16 + lr;
            bf[nn]     = *(const bf16x8*)&WT[(size_t)cv * 128 + koff];
            bf[nn + 4] = *(const bf16x8*)&WT[(size_t)(128 + cv) * 128 + koff];
        }
    };
    auto do_mfma = [&](bf16x8* af, bf16x8* bf) {
        #pragma unroll
        for (int m = 0; m < 2; m++)
            #pragma unroll
            for (int nn = 0; nn < 8; nn++)
                acc[m][nn] = __builtin_amdgcn_mfma_f32_16x16x32_bf16(af[m], bf[nn], acc[m][nn], 0, 0, 0);
    };

    bf16x8 afA[2], bfA[8], afB[2], bfB[8];
    load_frag(0, afA, bfA);
    #pragma unroll
    for (int ks = 0; ks < 4; ks += 2) {
        load_frag(ks + 1, afB, bfB);      // prefetch odd step
        do_mfma(afA, bfA);
        if (ks + 2 < 4) load_frag(ks + 2, afA, bfA);   // prefetch next even step
        do_mfma(afB, bfB);
    }

    #pragma unroll
    for (int m = 0; m < 2; m++) {
        int rb = row0 + wm * 32 + m * 16 + lk * 4;
        #pragma unroll
        for (int nn = 0; nn < 4; nn++) {
            int cv = wn * 64 + nn * 16 + lr;          // 0..127
            float biv = bias[cv];
            float bit = bias[128 + cv];
            #pragma unroll
            for (int j = 0; j < 4; j++) {
                int r = rb + j;
                if (r >= n) continue;
                float win = inrm[r];
                float won = onrm[r];
                float ge = bf2f((uint)gid[(size_t)r * 128 + cv]);
                float tv = acc[m][nn][j] * win + biv + ge;
                float tt = acc[m][nn + 4][j] * win + bit + ge;
                float lv = lrelu(tv), lt = lrelu(tt);
                out[(size_t)r * 384 + 128 + cv] = 0.5f * (lv + lt);
                uint pk = (uint)f2bf(lv * won) | ((uint)f2bf(lt * won) << 16);
                *(uint*)&xhat_sc[(size_t)r * 256 + 2 * cv] = pk;
            }
        }
    }
}

// ------- conv2 MFMA GEMM, LDS-free, depth-2 pipelined: 64r x 128c / block, K=384 --------
__global__ __launch_bounds__(256) void k_gemm2(
    const ushort* __restrict__ A, const ushort* __restrict__ WT,
    const float* __restrict__ inrm, const ushort* __restrict__ gid,
    const float* __restrict__ bias, float* __restrict__ out, int n)
{
    int tid  = threadIdx.x;
    int lane = tid & 63;
    int w    = tid >> 6;
    int wm   = w >> 1, wn = w & 1;
    int row0 = blockIdx.x * 64;
    int lr = lane & 15;
    int lk = lane >> 4;

    f32x4 acc[2][4];
    f32x4 zero = {0.f, 0.f, 0.f, 0.f};
    #pragma unroll
    for (int m = 0; m < 2; m++)
        #pragma unroll
        for (int nn = 0; nn < 4; nn++) acc[m][nn] = zero;

    int rg[2]; bool ok[2];
    #pragma unroll
    for (int m = 0; m < 2; m++) { rg[m] = row0 + wm * 32 + m * 16 + lr; ok[m] = rg[m] < n; }
    bf16x8 zf = {0, 0, 0, 0, 0, 0, 0, 0};

    auto load_frag = [&](int ks, bf16x8* af, bf16x8* bf) {
        int koff = ks * 32 + lk * 8;
        #pragma unroll
        for (int m = 0; m < 2; m++)
            af[m] = ok[m] ? *(const bf16x8*)&A[(size_t)rg[m] * 384 + koff] : zf;
        #pragma unroll
        for (int nn = 0; nn < 4; nn++) {
            int cg = wn * 64 + nn * 16 + lr;
            bf[nn] = *(const bf16x8*)&WT[(size_t)cg * 384 + koff];
        }
    };
    auto do_mfma = [&](bf16x8* af, bf16x8* bf) {
        #pragma unroll
        for (int m = 0; m < 2; m++)
            #pragma unroll
            for (int nn = 0; nn < 4; nn++)
                acc[m][nn] = __builtin_amdgcn_mfma_f32_16x16x32_bf16(af[m], bf[nn], acc[m][nn], 0, 0, 0);
    };

    bf16x8 afA[2], bfA[4], afB[2], bfB[4];
    load_frag(0, afA, bfA);
    #pragma unroll
    for (int ks = 0; ks < 12; ks += 2) {
        load_frag(ks + 1, afB, bfB);
        do_mfma(afA, bfA);
        if (ks + 2 < 12) load_frag(ks + 2, afA, bfA);
        do_mfma(afB, bfB);
    }

    #pragma unroll
    for (int m = 0; m < 2; m++) {
        int rb = row0 + wm * 32 + m * 16 + lk * 4;
        #pragma unroll
        for (int nn = 0; nn < 4; nn++) {
            int cg = wn * 64 + nn * 16 + lr;
            float bi = bias[cg];
            #pragma unroll
            for (int j = 0; j < 4; j++) {
                int r = rb + j;
                if (r >= n) continue;
                float ge = bf2f((uint)gid[(size_t)r * 128 + cg]);
                float t = acc[m][nn][j] * inrm[r] + bi + ge;
                out[(size_t)r * 384 + 256 + cg] = t;
            }
        }
    }
}

extern "C" void kernel_launch(void* const* d_in, const int* in_sizes, int n_in,
                              void* d_out, int out_size, void* d_ws, size_t ws_size,
                              hipStream_t stream) {
    const float* x      = (const float*)d_in[0];
    const float* id_emb = (const float*)d_in[1];
    const float* Wv0    = (const float*)d_in[2];
    const float* bv0    = (const float*)d_in[3];
    const float* Wv1    = (const float*)d_in[4];
    const float* bv1    = (const float*)d_in[5];
    const float* Wt0    = (const float*)d_in[6];
    const float* bt0    = (const float*)d_in[7];
    const float* Wt1    = (const float*)d_in[8];
    const float* bt1    = (const float*)d_in[9];
    const int*   src    = (const int*)d_in[10];
    const int*   dst    = (const int*)d_in[11];
    const int*   dsti   = (const int*)d_in[12];
    const int E = in_sizes[10];
    const int N = in_sizes[12];
    float* out = (float*)d_out;

    char* p = (char*)d_ws;
    ushort* xn_sc   = (ushort*)p; p += (size_t)N * 128 * 2;
    ushort* xhat_sc = (ushort*)p; p += (size_t)N * 256 * 2;
    ushort* z1      = (ushort*)p; p += (size_t)N * 128 * 2;
    ushort* zbig    = (ushort*)p; p += (size_t)N * 384 * 2;
    ushort* gid     = (ushort*)p; p += (size_t)N * 128 * 2;
    ushort* W1T     = (ushort*)p; p += 256 * 128 * 2;
    ushort* W2T     = (ushort*)p; p += 128 * 384 * 2;
    float* bias_cat = (float*)p;  p += 256 * 4;
    float* bias2    = (float*)p;  p += 128 * 4;
    float* onrm     = (float*)p;  p += (size_t)N * 4;
    float* inrm     = (float*)p;  p += (size_t)N * 4;
    int* deg_out    = (int*)p;    p += (size_t)N * 4;
    int* deg_in     = (int*)p;    p += (size_t)N * 4;
    int* cursor     = (int*)p;    p += (size_t)N * 4;
    int* row_ptr    = (int*)p;    p += (size_t)(N + 1) * 4;
    int* csum       = (int*)p;    p += 1024 * 4;
    int* col        = (int*)p;    p += (size_t)E * 4;

    hipMemsetAsync(deg_out, 0, (size_t)N * 3 * 4, stream);   // deg_out|deg_in|cursor contiguous

    int be = (E + 255) / 256;
    int bn = (N + 255) / 256;
    int bw = (N * 64 + 255) / 256;          // one wave per row
    int bg = (N + 63) / 64;                 // 64-row GEMM tiles
    int nb = (N + 1023) / 1024;             // scan chunks

    k_degrees<<<be, 256, 0, stream>>>(src, dst, deg_out, deg_in, E);
    k_norms  <<<bn, 256, 0, stream>>>(deg_out, deg_in, onrm, inrm, N);
    k_scan1  <<<nb, 1024, 0, stream>>>(deg_in, row_ptr, csum, N);
    k_scan2  <<<1, 1024, 0, stream>>>(csum, nb);
    k_scan3  <<<bn, 256, 0, stream>>>(row_ptr, csum, N);
    k_fill   <<<be, 256, 0, stream>>>(src, dst, row_ptr, cursor, col, E);
    k_wprep  <<<192, 256, 0, stream>>>(Wv0, Wt0, Wv1, Wt1, bv0, bt0, bv1, bt1,
                                       W1T, W2T, bias_cat, bias2);
    k_normx  <<<bw, 256, 0, stream>>>(x, onrm, dsti, id_emb, xn_sc, gid, out, N);

    k_agg1 <<<bw, 256, 0, stream>>>(xn_sc, row_ptr, col, z1, zbig, N);
    k_gemm1<<<bg, 256, 0, stream>>>(z1, W1T, inrm, onrm, gid, bias_cat, xhat_sc, out, N);
    k_agg2 <<<bw, 256, 0, stream>>>(xhat_sc, row_ptr, col, zbig, N);
    k_gemm2<<<bg, 256, 0, stream>>>(zbig, W2T, inrm, gid, bias2, out, N);
}

// Round 10
// 368.340 us; speedup vs baseline: 1.1012x; 1.1012x over previous
//
#include <hip/hip_runtime.h>
#include <math.h>

// MMGCN: GEMM pushed through the (linear) aggregation + m97-style MFMA GEMMs.
//   z1  = A . (xn*onrm)                      [shared by v,t]   -> conv1 GEMM K=128
//   zlx = A . leaky(xn*onrm)                 [shared by v,t]   -> conv2 top half
//   zx  = A . leaky(xhat_{v,t}*onrm) interleaved               -> conv2 bottom half
//   out256 = ([zlx | zx] @ B2)*in_norm + 0.5(b1v+b1t) + gid    -> one K=384 GEMM
// GEMMs: 128x128 tile, BK=64, 4 waves, global_load_lds (16B DMA) staging with
// XOR-swizzled source addresses + swizzled ds_read_b128 (linear LDS dest, rule #21).
// 32KB LDS/block -> 4-5 blocks/CU -> cross-block overlap hides barrier drains (m114/m97).

typedef unsigned int uint;
typedef unsigned short ushort;
using bf16x8 = __attribute__((ext_vector_type(8))) short;
using f32x4  = __attribute__((ext_vector_type(4))) float;

__device__ __forceinline__ float lrelu(float v) { return v >= 0.0f ? v : 0.01f * v; }
__device__ __forceinline__ float bf2f(uint us) { return __uint_as_float(us << 16); }
__device__ __forceinline__ ushort f2bf(float f) {
    uint u = __float_as_uint(f);
    u += 0x7fffu + ((u >> 16) & 1u);   // round-to-nearest-even
    return (ushort)(u >> 16);
}
__device__ __forceinline__ void stage16(const ushort* g, ushort* l) {
    __builtin_amdgcn_global_load_lds(
        (const __attribute__((address_space(1))) void*)(g),
        (__attribute__((address_space(3))) void*)(l), 16, 0, 0);
}

// ---------------- degree histograms ----------------
__global__ void k_degrees(const int* __restrict__ src, const int* __restrict__ dst,
                          int* __restrict__ deg_out, int* __restrict__ deg_in, int E) {
    int e = blockIdx.x * blockDim.x + threadIdx.x;
    if (e < E) {
        atomicAdd(&deg_out[src[e]], 1);
        atomicAdd(&deg_in[dst[e]], 1);
    }
}

__global__ void k_norms(const int* __restrict__ deg_out, const int* __restrict__ deg_in,
                        float* __restrict__ onrm, float* __restrict__ inrm, int n) {
    int i = blockIdx.x * blockDim.x + threadIdx.x;
    if (i < n) {
        onrm[i] = 1.0f / sqrtf((float)max(deg_out[i], 1));
        inrm[i] = 1.0f / sqrtf((float)max(deg_in[i], 1));
    }
}

// ---------------- multi-block prefix scan: deg_in -> row_ptr ----------------
__global__ void k_scan1(const int* __restrict__ deg, int* __restrict__ row_ptr,
                        int* __restrict__ csum, int n) {
    __shared__ int wsum[16];
    __shared__ int wpre[16];
    int lane = threadIdx.x & 63;
    int wid  = threadIdx.x >> 6;
    int i = blockIdx.x * 1024 + threadIdx.x;
    int v = (i < n) ? deg[i] : 0;
    int s = v;
    #pragma unroll
    for (int off = 1; off < 64; off <<= 1) {
        int t = __shfl_up(s, off, 64);
        if (lane >= off) s += t;
    }
    if (lane == 63) wsum[wid] = s;
    __syncthreads();
    if (wid == 0) {
        int wv = (lane < 16) ? wsum[lane] : 0;
        int ss = wv;
        #pragma unroll
        for (int off = 1; off < 16; off <<= 1) {
            int t = __shfl_up(ss, off, 64);
            if (lane >= off) ss += t;
        }
        if (lane < 16) wpre[lane] = ss - wv;
    }
    __syncthreads();
    int incl = s + wpre[wid];
    if (i < n) row_ptr[i + 1] = incl;                        // chunk-local for now
    if (threadIdx.x == 1023) csum[blockIdx.x] = incl;        // chunk total
}

__global__ void k_scan2(int* __restrict__ csum, int nb) {
    __shared__ int wsum[16];
    __shared__ int wpre[16];
    int lane = threadIdx.x & 63;
    int wid  = threadIdx.x >> 6;
    int i = threadIdx.x;
    int v = (i < nb) ? csum[i] : 0;
    int s = v;
    #pragma unroll
    for (int off = 1; off < 64; off <<= 1) {
        int t = __shfl_up(s, off, 64);
        if (lane >= off) s += t;
    }
    if (lane == 63) wsum[wid] = s;
    __syncthreads();
    if (wid == 0) {
        int wv = (lane < 16) ? wsum[lane] : 0;
        int ss = wv;
        #pragma unroll
        for (int off = 1; off < 16; off <<= 1) {
            int t = __shfl_up(ss, off, 64);
            if (lane >= off) ss += t;
        }
        if (lane < 16) wpre[lane] = ss - wv;
    }
    __syncthreads();
    if (i < nb) csum[i] = s + wpre[wid];
}

__global__ void k_scan3(int* __restrict__ row_ptr, const int* __restrict__ csum, int n) {
    int i = blockIdx.x * blockDim.x + threadIdx.x;
    if (i == 0) row_ptr[0] = 0;
    if (i < n) {
        int b = i >> 10;
        if (b > 0) row_ptr[i + 1] += csum[b - 1];
    }
}

__global__ void k_fill(const int* __restrict__ src, const int* __restrict__ dst,
                       const int* __restrict__ row_ptr, int* __restrict__ cursor,
                       int* __restrict__ col, int E) {
    int e = blockIdx.x * blockDim.x + threadIdx.x;
    if (e < E) {
        int d = dst[e];
        int pos = atomicAdd(&cursor[d], 1);
        col[row_ptr[d] + pos] = src[e];
    }
}

// ---------------- weight prep ----------------
// W1T [256 rows][128 k]: row h*128+p: p<64 -> Wv0 col (h*64+p); p>=64 -> Wt0 col (h*64+p-64)
//   (so each 128-row half h holds matching v/t column pairs for one GEMM1 block)
// W2T [128 rows][384 k]: k 0:128 = 0.5(Wv1+Wt1); k 128+2q+b = 0.5 Wb1[128+q]  (interleaved)
__global__ void k_wprep(const float* __restrict__ Wv0, const float* __restrict__ Wt0,
                        const float* __restrict__ Wv1, const float* __restrict__ Wt1,
                        const float* __restrict__ bv0, const float* __restrict__ bt0,
                        const float* __restrict__ bv1, const float* __restrict__ bt1,
                        ushort* __restrict__ W1T, ushort* __restrict__ W2T,
                        float* __restrict__ bias_cat, float* __restrict__ bias2) {
    int t = blockIdx.x * blockDim.x + threadIdx.x;
    if (t < 256 * 128) {
        int cp = t >> 7, k = t & 127;
        int p = cp & 127;
        int col = ((cp >> 7) << 6) + (p & 63);
        float v = (p < 64) ? Wv0[k * 128 + col] : Wt0[k * 128 + col];
        W1T[cp * 128 + k] = f2bf(v);
    }
    if (t < 128 * 384) {
        int c = t / 384, r = t % 384;
        float v;
        if (r < 128) v = 0.5f * (Wv1[r * 128 + c] + Wt1[r * 128 + c]);
        else {
            int q = (r - 128) >> 1;
            v = 0.5f * (((r - 128) & 1) ? Wt1[(128 + q) * 128 + c] : Wv1[(128 + q) * 128 + c]);
        }
        W2T[c * 384 + r] = f2bf(v);
    }
    if (t < 256) {
        int p = t & 127;
        int col = ((t >> 7) << 6) + (p & 63);
        bias_cat[t] = (p < 64) ? bv0[col] : bt0[col];
    }
    if (t < 128) bias2[t] = 0.5f * (bv1[t] + bt1[t]);
}

// ------- row L2-normalize x; out[:,0:128]=leaky(xn); xn_sc=xn*onrm (bf16); gid bf16 -------
__global__ void k_normx(const float* __restrict__ x, const float* __restrict__ onrm,
                        const int* __restrict__ dsti, const float* __restrict__ id_emb,
                        ushort* __restrict__ xn_sc, ushort* __restrict__ gid,
                        float* __restrict__ out, int n) {
    int gtid = blockIdx.x * blockDim.x + threadIdx.x;
    int row  = gtid >> 6;
    int lane = gtid & 63;
    if (row >= n) return;
    int c = lane * 2;
    float2 v = *(const float2*)&x[(size_t)row * 128 + c];
    float s = v.x * v.x + v.y * v.y;
    #pragma unroll
    for (int off = 1; off < 64; off <<= 1) s += __shfl_xor(s, off, 64);
    float scale = 1.0f / fmaxf(sqrtf(s), 1e-12f);
    float nx = v.x * scale, ny = v.y * scale;
    *(float2*)&out[(size_t)row * 384 + c] = make_float2(lrelu(nx), lrelu(ny));
    float so = onrm[row];
    uint p = (uint)f2bf(nx * so) | ((uint)f2bf(ny * so) << 16);
    *(uint*)&xn_sc[(size_t)row * 128 + c] = p;
    int g = dsti[row];
    float2 ge = *(const float2*)&id_emb[(size_t)g * 128 + c];
    uint pg = (uint)f2bf(ge.x) | ((uint)f2bf(ge.y) << 16);
    *(uint*)&gid[(size_t)row * 128 + c] = pg;
}

// ---------------- gather pass 1: z1 = A.xn_sc ; zlx = A.leaky(xn_sc)  (both bf16) -------
__global__ void k_agg1(const ushort* __restrict__ xn_sc, const int* __restrict__ rp,
                       const int* __restrict__ col, ushort* __restrict__ z1,
                       ushort* __restrict__ zbig, int n) {
    int gtid = blockIdx.x * blockDim.x + threadIdx.x;
    int row  = gtid >> 6;
    int lane = gtid & 63;
    if (row >= n) return;
    int c = lane * 2;
    float zx = 0.f, zy = 0.f, lx = 0.f, ly = 0.f;
    int e0 = rp[row], e1 = rp[row + 1];
    int e = e0;
    for (; e + 1 < e1; e += 2) {
        int s0 = col[e], s1 = col[e + 1];
        uint v0 = *(const uint*)&xn_sc[(size_t)s0 * 128 + c];
        uint v1 = *(const uint*)&xn_sc[(size_t)s1 * 128 + c];
        float ax = bf2f(v0 & 0xffffu), ay = bf2f(v0 >> 16);
        float bx = bf2f(v1 & 0xffffu), by = bf2f(v1 >> 16);
        zx += ax + bx; zy += ay + by;
        lx += lrelu(ax) + lrelu(bx); ly += lrelu(ay) + lrelu(by);
    }
    if (e < e1) {
        uint v0 = *(const uint*)&xn_sc[(size_t)col[e] * 128 + c];
        float ax = bf2f(v0 & 0xffffu), ay = bf2f(v0 >> 16);
        zx += ax; zy += ay; lx += lrelu(ax); ly += lrelu(ay);
    }
    *(uint*)&z1[(size_t)row * 128 + c]  = (uint)f2bf(zx) | ((uint)f2bf(zy) << 16);
    *(uint*)&zbig[(size_t)row * 384 + c] = (uint)f2bf(lx) | ((uint)f2bf(ly) << 16);
}

// ---------------- gather pass 2: zx_inter = A.xhat_sc  (256-wide, bf16) ----------------
__global__ void k_agg2(const ushort* __restrict__ xhat_sc, const int* __restrict__ rp,
                       const int* __restrict__ col, ushort* __restrict__ zbig, int n) {
    int gtid = blockIdx.x * blockDim.x + threadIdx.x;
    int row  = gtid >> 6;
    int lane = gtid & 63;
    if (row >= n) return;
    int c = lane * 4;
    float a0 = 0.f, a1 = 0.f, a2 = 0.f, a3 = 0.f;
    int e0 = rp[row], e1 = rp[row + 1];
    int e = e0;
    for (; e + 1 < e1; e += 2) {
        int s0 = col[e], s1 = col[e + 1];
        uint2 v0 = *(const uint2*)&xhat_sc[(size_t)s0 * 256 + c];
        uint2 v1 = *(const uint2*)&xhat_sc[(size_t)s1 * 256 + c];
        a0 += bf2f(v0.x & 0xffffu) + bf2f(v1.x & 0xffffu);
        a1 += bf2f(v0.x >> 16)     + bf2f(v1.x >> 16);
        a2 += bf2f(v0.y & 0xffffu) + bf2f(v1.y & 0xffffu);
        a3 += bf2f(v0.y >> 16)     + bf2f(v1.y >> 16);
    }
    if (e < e1) {
        uint2 v0 = *(const uint2*)&xhat_sc[(size_t)col[e] * 256 + c];
        a0 += bf2f(v0.x & 0xffffu); a1 += bf2f(v0.x >> 16);
        a2 += bf2f(v0.y & 0xffffu); a3 += bf2f(v0.y >> 16);
    }
    uint2 p;
    p.x = (uint)f2bf(a0) | ((uint)f2bf(a1) << 16);
    p.y = (uint)f2bf(a2) | ((uint)f2bf(a3) << 16);
    *(uint2*)&zbig[(size_t)row * 384 + 128 + c] = p;
}

// ---- m97-style MFMA GEMM: 128 rows x 128 cols, BK=64, global_load_lds + XOR swizzle ----
// EPI==1 (conv1, grid.y=h in {0,1}): block cols = W1T rows [h*128, h*128+128), i.e.
//   v-cols h*64..+63 (p<64) and matching t-cols (p>=64). Wave wn owns 32 v + 32 t pairs.
// EPI==2 (conv2): plain 128 out cols; out[:,256+c] = acc*in_norm + bias2 + gid.
template<int K, int LDA, int EPI>
__global__ __launch_bounds__(256) void k_gemm(
    const ushort* __restrict__ A, const ushort* __restrict__ WT,
    const float* __restrict__ inrm, const float* __restrict__ onrm,
    const ushort* __restrict__ gid, const float* __restrict__ bias,
    ushort* __restrict__ xhat_sc, float* __restrict__ out, int n)
{
    __shared__ __align__(16) ushort As[128 * 64];
    __shared__ __align__(16) ushort Bs[128 * 64];
    int tid  = threadIdx.x;
    int lane = tid & 63;
    int w    = tid >> 6;
    int wm   = w >> 1, wn = w & 1;
    int lr   = lane & 15, lk = lane >> 4;
    int row0 = blockIdx.x * 128;
    int h    = blockIdx.y;
    int cb   = h * 128;                          // B row base in WT

    // staging geometry: wave w stages granules [w*256, w*256+256) of each tile (4 calls x 64).
    // LDS is written LINEARLY (DMA requirement); the XOR swizzle is applied to the global
    // SOURCE column so that ds_read with the same XOR retrieves the right data (rule #21).
    const ushort* aSrc[4]; const ushort* bSrc[4]; int dOff[4];
    #pragma unroll
    for (int q = 0; q < 4; q++) {
        int g = w * 256 + q * 64 + lane;
        int row = g >> 3, lc = g & 7;
        int scol = ((lc ^ (row & 7)) << 3);
        aSrc[q] = A  + (size_t)(row0 + row) * LDA + scol;   // OOB rows read into ws (harmless, unused)
        bSrc[q] = WT + (size_t)(cb + row) * K + scol;
        dOff[q] = (w * 256 + q * 64) * 8;                   // wave-uniform element offset
    }

    f32x4 acc[4][4];
    f32x4 zero = {0.f, 0.f, 0.f, 0.f};
    #pragma unroll
    for (int m = 0; m < 4; m++)
        #pragma unroll
        for (int nn = 0; nn < 4; nn++) acc[m][nn] = zero;

    int sw = (lr & 7);
    const char* ab = (const char*)As;
    const char* bb = (const char*)Bs;

    for (int ks = 0; ks < K / 64; ks++) {
        int k0 = ks * 64;
        #pragma unroll
        for (int q = 0; q < 4; q++) {
            stage16(aSrc[q] + k0, As + dOff[q]);
            stage16(bSrc[q] + k0, Bs + dOff[q]);
        }
        __syncthreads();
        #pragma unroll
        for (int kk = 0; kk < 2; kk++) {
            bf16x8 af[4], bf[4];
            #pragma unroll
            for (int m = 0; m < 4; m++) {
                int row = wm * 64 + m * 16 + lr;
                af[m] = *(const bf16x8*)(ab + row * 128 + (((kk * 4 + lk) ^ sw) << 4));
            }
            #pragma unroll
            for (int nn = 0; nn < 4; nn++) {
                int brow = (EPI == 1)
                    ? ((nn & 2) ? 64 : 0) + wn * 32 + (nn & 1) * 16 + lr
                    : wn * 64 + nn * 16 + lr;
                bf[nn] = *(const bf16x8*)(bb + brow * 128 + (((kk * 4 + lk) ^ sw) << 4));
            }
            #pragma unroll
            for (int m = 0; m < 4; m++)
                #pragma unroll
                for (int nn = 0; nn < 4; nn++)
                    acc[m][nn] = __builtin_amdgcn_mfma_f32_16x16x32_bf16(af[m], bf[nn], acc[m][nn], 0, 0, 0);
        }
        __syncthreads();
    }

    #pragma unroll
    for (int m = 0; m < 4; m++) {
        int rb = row0 + wm * 64 + m * 16 + lk * 4;
        if (EPI == 1) {
            #pragma unroll
            for (int nn = 0; nn < 2; nn++) {
                int po = wn * 32 + nn * 16 + lr;          // 0..63 within half
                int cv = h * 64 + po;                     // global v/t column 0..127
                float biv = bias[h * 128 + po];
                float bit = bias[h * 128 + 64 + po];
                #pragma unroll
                for (int j = 0; j < 4; j++) {
                    int r = rb + j;
                    if (r >= n) continue;
                    float win = inrm[r];
                    float won = onrm[r];
                    float ge = bf2f((uint)gid[(size_t)r * 128 + cv]);
                    float tv = acc[m][nn][j] * win + biv + ge;
                    float tt = acc[m][nn + 2][j] * win + bit + ge;
                    float lv = lrelu(tv), lt = lrelu(tt);
                    out[(size_t)r * 384 + 128 + cv] = 0.5f * (lv + lt);
                    uint pk = (uint)f2bf(lv * won) | ((uint)f2bf(lt * won) << 16);
                    *(uint*)&xhat_sc[(size_t)r * 256 + 2 * cv] = pk;
                }
            }
        } else {
            #pragma unroll
            for (int nn = 0; nn < 4; nn++) {
                int cg = wn * 64 + nn * 16 + lr;
                float bi = bias[cg];
                #pragma unroll
                for (int j = 0; j < 4; j++) {
                    int r = rb + j;
                    if (r >= n) continue;
                    float ge = bf2f((uint)gid[(size_t)r * 128 + cg]);
                    float t = acc[m][nn][j] * inrm[r] + bi + ge;
                    out[(size_t)r * 384 + 256 + cg] = t;
                }
            }
        }
    }
}

extern "C" void kernel_launch(void* const* d_in, const int* in_sizes, int n_in,
                              void* d_out, int out_size, void* d_ws, size_t ws_size,
                              hipStream_t stream) {
    const float* x      = (const float*)d_in[0];
    const float* id_emb = (const float*)d_in[1];
    const float* Wv0    = (const float*)d_in[2];
    const float* bv0    = (const float*)d_in[3];
    const float* Wv1    = (const float*)d_in[4];
    const float* bv1    = (const float*)d_in[5];
    const float* Wt0    = (const float*)d_in[6];
    const float* bt0    = (const float*)d_in[7];
    const float* Wt1    = (const float*)d_in[8];
    const float* bt1    = (const float*)d_in[9];
    const int*   src    = (const int*)d_in[10];
    const int*   dst    = (const int*)d_in[11];
    const int*   dsti   = (const int*)d_in[12];
    const int E = in_sizes[10];
    const int N = in_sizes[12];
    float* out = (float*)d_out;

    char* p = (char*)d_ws;
    ushort* xn_sc   = (ushort*)p; p += (size_t)N * 128 * 2;
    ushort* xhat_sc = (ushort*)p; p += (size_t)N * 256 * 2;
    ushort* z1      = (ushort*)p; p += (size_t)N * 128 * 2;
    ushort* zbig    = (ushort*)p; p += (size_t)N * 384 * 2;
    ushort* gid     = (ushort*)p; p += (size_t)N * 128 * 2;
    ushort* W1T     = (ushort*)p; p += 256 * 128 * 2;
    ushort* W2T     = (ushort*)p; p += 128 * 384 * 2;
    float* bias_cat = (float*)p;  p += 256 * 4;
    float* bias2    = (float*)p;  p += 128 * 4;
    float* onrm     = (float*)p;  p += (size_t)N * 4;
    float* inrm     = (float*)p;  p += (size_t)N * 4;
    int* deg_out    = (int*)p;    p += (size_t)N * 4;
    int* deg_in     = (int*)p;    p += (size_t)N * 4;
    int* cursor     = (int*)p;    p += (size_t)N * 4;
    int* row_ptr    = (int*)p;    p += (size_t)(N + 1) * 4;
    int* csum       = (int*)p;    p += 1024 * 4;
    int* col        = (int*)p;    p += (size_t)E * 4;

    hipMemsetAsync(deg_out, 0, (size_t)N * 3 * 4, stream);   // deg_out|deg_in|cursor contiguous

    int be = (E + 255) / 256;
    int bn = (N + 255) / 256;
    int bw = (N * 64 + 255) / 256;          // one wave per row
    int bg = (N + 127) / 128;               // 128-row GEMM tiles
    int nb = (N + 1023) / 1024;             // scan chunks

    k_degrees<<<be, 256, 0, stream>>>(src, dst, deg_out, deg_in, E);
    k_norms  <<<bn, 256, 0, stream>>>(deg_out, deg_in, onrm, inrm, N);
    k_scan1  <<<nb, 1024, 0, stream>>>(deg_in, row_ptr, csum, N);
    k_scan2  <<<1, 1024, 0, stream>>>(csum, nb);
    k_scan3  <<<bn, 256, 0, stream>>>(row_ptr, csum, N);
    k_fill   <<<be, 256, 0, stream>>>(src, dst, row_ptr, cursor, col, E);
    k_wprep  <<<192, 256, 0, stream>>>(Wv0, Wt0, Wv1, Wt1, bv0, bt0, bv1, bt1,
                                       W1T, W2T, bias_cat, bias2);
    k_normx  <<<bw, 256, 0, stream>>>(x, onrm, dsti, id_emb, xn_sc, gid, out, N);

    k_agg1<<<bw, 256, 0, stream>>>(xn_sc, row_ptr, col, z1, zbig, N);
    k_gemm<128, 128, 1><<<dim3(bg, 2), 256, 0, stream>>>(
        z1, W1T, inrm, onrm, gid, bias_cat, xhat_sc, out, N);
    k_agg2<<<bw, 256, 0, stream>>>(xhat_sc, row_ptr, col, zbig, N);
    k_gemm<384, 384, 2><<<dim3(bg, 1), 256, 0, stream>>>(
        zbig, W2T, inrm, onrm, gid, bias2, xhat_sc, out, N);
}

// Round 11
// 330.095 us; speedup vs baseline: 1.2288x; 1.1159x over previous
//
#include <hip/hip_runtime.h>
#include <math.h>

// MMGCN: both GEMMs pushed through the (linear) aggregations.
//   z1 = A.(xn*onrm)                                -> conv1 GEMM K=128 (shared v,t)
//   qin = [leaky(xn*onrm) | leaky(xhat*onrm) interleaved]  (per node, bf16)
//   q   = qin @ W2  (K=384 GEMM, PRE-aggregation)   -> conv2 now gathers 128-wide q
//   out256 = agg(q)*in_norm + 0.5(b1v+b1t) + gid    (fused into the gather)
// GEMMs: m97 structure — 128x128 tile, BK=64, 4 waves, global_load_lds (16B DMA),
// XOR-swizzled source + swizzled ds_read_b128 (linear LDS dest, rule #21).

typedef unsigned int uint;
typedef unsigned short ushort;
using bf16x8 = __attribute__((ext_vector_type(8))) short;
using f32x4  = __attribute__((ext_vector_type(4))) float;

__device__ __forceinline__ float lrelu(float v) { return v >= 0.0f ? v : 0.01f * v; }
__device__ __forceinline__ float bf2f(uint us) { return __uint_as_float(us << 16); }
__device__ __forceinline__ ushort f2bf(float f) {
    uint u = __float_as_uint(f);
    u += 0x7fffu + ((u >> 16) & 1u);   // round-to-nearest-even
    return (ushort)(u >> 16);
}
__device__ __forceinline__ void stage16(const ushort* g, ushort* l) {
    __builtin_amdgcn_global_load_lds(
        (const __attribute__((address_space(1))) void*)(g),
        (__attribute__((address_space(3))) void*)(l), 16, 0, 0);
}

// ---------------- degree histograms ----------------
__global__ void k_degrees(const int* __restrict__ src, const int* __restrict__ dst,
                          int* __restrict__ deg_out, int* __restrict__ deg_in, int E) {
    int e = blockIdx.x * blockDim.x + threadIdx.x;
    if (e < E) {
        atomicAdd(&deg_out[src[e]], 1);
        atomicAdd(&deg_in[dst[e]], 1);
    }
}

__global__ void k_norms(const int* __restrict__ deg_out, const int* __restrict__ deg_in,
                        float* __restrict__ onrm, float* __restrict__ inrm, int n) {
    int i = blockIdx.x * blockDim.x + threadIdx.x;
    if (i < n) {
        onrm[i] = 1.0f / sqrtf((float)max(deg_out[i], 1));
        inrm[i] = 1.0f / sqrtf((float)max(deg_in[i], 1));
    }
}

// ---------------- multi-block prefix scan: deg_in -> row_ptr ----------------
__global__ void k_scan1(const int* __restrict__ deg, int* __restrict__ row_ptr,
                        int* __restrict__ csum, int n) {
    __shared__ int wsum[16];
    __shared__ int wpre[16];
    int lane = threadIdx.x & 63;
    int wid  = threadIdx.x >> 6;
    int i = blockIdx.x * 1024 + threadIdx.x;
    int v = (i < n) ? deg[i] : 0;
    int s = v;
    #pragma unroll
    for (int off = 1; off < 64; off <<= 1) {
        int t = __shfl_up(s, off, 64);
        if (lane >= off) s += t;
    }
    if (lane == 63) wsum[wid] = s;
    __syncthreads();
    if (wid == 0) {
        int wv = (lane < 16) ? wsum[lane] : 0;
        int ss = wv;
        #pragma unroll
        for (int off = 1; off < 16; off <<= 1) {
            int t = __shfl_up(ss, off, 64);
            if (lane >= off) ss += t;
        }
        if (lane < 16) wpre[lane] = ss - wv;
    }
    __syncthreads();
    int incl = s + wpre[wid];
    if (i < n) row_ptr[i + 1] = incl;                        // chunk-local for now
    if (threadIdx.x == 1023) csum[blockIdx.x] = incl;        // chunk total
}

__global__ void k_scan2(int* __restrict__ csum, int nb) {
    __shared__ int wsum[16];
    __shared__ int wpre[16];
    int lane = threadIdx.x & 63;
    int wid  = threadIdx.x >> 6;
    int i = threadIdx.x;
    int v = (i < nb) ? csum[i] : 0;
    int s = v;
    #pragma unroll
    for (int off = 1; off < 64; off <<= 1) {
        int t = __shfl_up(s, off, 64);
        if (lane >= off) s += t;
    }
    if (lane == 63) wsum[wid] = s;
    __syncthreads();
    if (wid == 0) {
        int wv = (lane < 16) ? wsum[lane] : 0;
        int ss = wv;
        #pragma unroll
        for (int off = 1; off < 16; off <<= 1) {
            int t = __shfl_up(ss, off, 64);
            if (lane >= off) ss += t;
        }
        if (lane < 16) wpre[lane] = ss - wv;
    }
    __syncthreads();
    if (i < nb) csum[i] = s + wpre[wid];
}

__global__ void k_scan3(int* __restrict__ row_ptr, const int* __restrict__ csum, int n) {
    int i = blockIdx.x * blockDim.x + threadIdx.x;
    if (i == 0) row_ptr[0] = 0;
    if (i < n) {
        int b = i >> 10;
        if (b > 0) row_ptr[i + 1] += csum[b - 1];
    }
}

__global__ void k_fill(const int* __restrict__ src, const int* __restrict__ dst,
                       const int* __restrict__ row_ptr, int* __restrict__ cursor,
                       int* __restrict__ col, int E) {
    int e = blockIdx.x * blockDim.x + threadIdx.x;
    if (e < E) {
        int d = dst[e];
        int pos = atomicAdd(&cursor[d], 1);
        col[row_ptr[d] + pos] = src[e];
    }
}

// ---------------- weight prep ----------------
// W1T [256 rows][128 k]: row h*128+p: p<64 -> Wv0 col (h*64+p); p>=64 -> Wt0 col (h*64+p-64)
// W2T [128 rows][384 k]: k 0:128 = 0.5(Wv1+Wt1); k 128+2q+b = 0.5 Wb1[128+q]  (interleaved)
__global__ void k_wprep(const float* __restrict__ Wv0, const float* __restrict__ Wt0,
                        const float* __restrict__ Wv1, const float* __restrict__ Wt1,
                        const float* __restrict__ bv0, const float* __restrict__ bt0,
                        const float* __restrict__ bv1, const float* __restrict__ bt1,
                        ushort* __restrict__ W1T, ushort* __restrict__ W2T,
                        float* __restrict__ bias_cat, float* __restrict__ bias2) {
    int t = blockIdx.x * blockDim.x + threadIdx.x;
    if (t < 256 * 128) {
        int cp = t >> 7, k = t & 127;
        int p = cp & 127;
        int col = ((cp >> 7) << 6) + (p & 63);
        float v = (p < 64) ? Wv0[k * 128 + col] : Wt0[k * 128 + col];
        W1T[cp * 128 + k] = f2bf(v);
    }
    if (t < 128 * 384) {
        int c = t / 384, r = t % 384;
        float v;
        if (r < 128) v = 0.5f * (Wv1[r * 128 + c] + Wt1[r * 128 + c]);
        else {
            int q = (r - 128) >> 1;
            v = 0.5f * (((r - 128) & 1) ? Wt1[(128 + q) * 128 + c] : Wv1[(128 + q) * 128 + c]);
        }
        W2T[c * 384 + r] = f2bf(v);
    }
    if (t < 256) {
        int p = t & 127;
        int col = ((t >> 7) << 6) + (p & 63);
        bias_cat[t] = (p < 64) ? bv0[col] : bt0[col];
    }
    if (t < 128) bias2[t] = 0.5f * (bv1[t] + bt1[t]);
}

// --- row L2-normalize x; out[:,0:128]=leaky(xn); xn_sc=xn*onrm; qin[:,0:128]=leaky(xn_sc);
//     gid = id_emb[dst_ids] densified (bf16) ---
__global__ void k_normx(const float* __restrict__ x, const float* __restrict__ onrm,
                        const int* __restrict__ dsti, const float* __restrict__ id_emb,
                        ushort* __restrict__ xn_sc, ushort* __restrict__ qin,
                        ushort* __restrict__ gid, float* __restrict__ out, int n) {
    int gtid = blockIdx.x * blockDim.x + threadIdx.x;
    int row  = gtid >> 6;
    int lane = gtid & 63;
    if (row >= n) return;
    int c = lane * 2;
    float2 v = *(const float2*)&x[(size_t)row * 128 + c];
    float s = v.x * v.x + v.y * v.y;
    #pragma unroll
    for (int off = 1; off < 64; off <<= 1) s += __shfl_xor(s, off, 64);
    float scale = 1.0f / fmaxf(sqrtf(s), 1e-12f);
    float nx = v.x * scale, ny = v.y * scale;
    *(float2*)&out[(size_t)row * 384 + c] = make_float2(lrelu(nx), lrelu(ny));
    float so = onrm[row];
    float sx = nx * so, sy = ny * so;
    *(uint*)&xn_sc[(size_t)row * 128 + c] = (uint)f2bf(sx) | ((uint)f2bf(sy) << 16);
    // conv2 top-half input: leaky(xn*onrm)  (onrm>0 so leaky commutes with the scale)
    *(uint*)&qin[(size_t)row * 384 + c] = (uint)f2bf(lrelu(sx)) | ((uint)f2bf(lrelu(sy)) << 16);
    int g = dsti[row];
    float2 ge = *(const float2*)&id_emb[(size_t)g * 128 + c];
    *(uint*)&gid[(size_t)row * 128 + c] = (uint)f2bf(ge.x) | ((uint)f2bf(ge.y) << 16);
}

// ---------------- gather pass 1: z1 = A.xn_sc  (bf16) ----------------
__global__ void k_agg1(const ushort* __restrict__ xn_sc, const int* __restrict__ rp,
                       const int* __restrict__ col, ushort* __restrict__ z1, int n) {
    int gtid = blockIdx.x * blockDim.x + threadIdx.x;
    int row  = gtid >> 6;
    int lane = gtid & 63;
    if (row >= n) return;
    int c = lane * 2;
    float zx = 0.f, zy = 0.f;
    int e0 = rp[row], e1 = rp[row + 1];
    int e = e0;
    for (; e + 1 < e1; e += 2) {
        int s0 = col[e], s1 = col[e + 1];
        uint v0 = *(const uint*)&xn_sc[(size_t)s0 * 128 + c];
        uint v1 = *(const uint*)&xn_sc[(size_t)s1 * 128 + c];
        zx += bf2f(v0 & 0xffffu) + bf2f(v1 & 0xffffu);
        zy += bf2f(v0 >> 16)     + bf2f(v1 >> 16);
    }
    if (e < e1) {
        uint v0 = *(const uint*)&xn_sc[(size_t)col[e] * 128 + c];
        zx += bf2f(v0 & 0xffffu); zy += bf2f(v0 >> 16);
    }
    *(uint*)&z1[(size_t)row * 128 + c] = (uint)f2bf(zx) | ((uint)f2bf(zy) << 16);
}

// ---------------- gather pass 2 + conv2 epilogue: out[:,256:384] ----------------
__global__ void k_agg2e(const ushort* __restrict__ q, const int* __restrict__ rp,
                        const int* __restrict__ col, const float* __restrict__ inrm,
                        const float* __restrict__ bias2, const ushort* __restrict__ gid,
                        float* __restrict__ out, int n) {
    int gtid = blockIdx.x * blockDim.x + threadIdx.x;
    int row  = gtid >> 6;
    int lane = gtid & 63;
    if (row >= n) return;
    int c = lane * 2;
    float ax = 0.f, ay = 0.f;
    int e0 = rp[row], e1 = rp[row + 1];
    int e = e0;
    for (; e + 1 < e1; e += 2) {
        int s0 = col[e], s1 = col[e + 1];
        uint v0 = *(const uint*)&q[(size_t)s0 * 128 + c];
        uint v1 = *(const uint*)&q[(size_t)s1 * 128 + c];
        ax += bf2f(v0 & 0xffffu) + bf2f(v1 & 0xffffu);
        ay += bf2f(v0 >> 16)     + bf2f(v1 >> 16);
    }
    if (e < e1) {
        uint v0 = *(const uint*)&q[(size_t)col[e] * 128 + c];
        ax += bf2f(v0 & 0xffffu); ay += bf2f(v0 >> 16);
    }
    float win = inrm[row];
    float2 bi = *(const float2*)&bias2[c];
    uint pg = *(const uint*)&gid[(size_t)row * 128 + c];
    float ox = ax * win + bi.x + bf2f(pg & 0xffffu);
    float oy = ay * win + bi.y + bf2f(pg >> 16);
    *(float2*)&out[(size_t)row * 384 + 256 + c] = make_float2(ox, oy);
}

// ---- m97-style MFMA GEMM: 128 rows x 128 cols, BK=64, global_load_lds + XOR swizzle ----
// EPI==1 (conv1, grid.y=h): cols = W1T rows [h*128,h*128+128) = v-cols h*64..+63 (p<64)
//   and matching t-cols (p>=64). Epilogue: out[:,128+cv]=0.5(leaky(tv)+leaky(tt));
//   qin[:,128+2cv..] = bf16(leaky(tv)*onrm, leaky(tt)*onrm)  (interleaved, for gemm_q).
// EPI==3 (gemm_q): q = A @ W2  (bf16 out, no epilogue fusion).
template<int K, int LDA, int EPI>
__global__ __launch_bounds__(256) void k_gemm(
    const ushort* __restrict__ A, const ushort* __restrict__ WT,
    const float* __restrict__ inrm, const float* __restrict__ onrm,
    const ushort* __restrict__ gid, const float* __restrict__ bias,
    ushort* __restrict__ xq, float* __restrict__ out, int n)
{
    __shared__ __align__(16) ushort As[128 * 64];
    __shared__ __align__(16) ushort Bs[128 * 64];
    int tid  = threadIdx.x;
    int lane = tid & 63;
    int w    = tid >> 6;
    int wm   = w >> 1, wn = w & 1;
    int lr   = lane & 15, lk = lane >> 4;
    int row0 = blockIdx.x * 128;
    int h    = blockIdx.y;
    int cb   = h * 128;                          // B row base in WT

    // wave w stages granules [w*256, w*256+256) of each tile. LDS written LINEARLY (DMA
    // requirement); XOR swizzle applied to the global SOURCE column and mirrored on the
    // ds_read side (rule #21).
    const ushort* aSrc[4]; const ushort* bSrc[4]; int dOff[4];
    #pragma unroll
    for (int q = 0; q < 4; q++) {
        int g = w * 256 + q * 64 + lane;
        int row = g >> 3, lc = g & 7;
        int scol = ((lc ^ (row & 7)) << 3);
        aSrc[q] = A  + (size_t)(row0 + row) * LDA + scol;   // OOB rows read ws junk (unused)
        bSrc[q] = WT + (size_t)(cb + row) * K + scol;
        dOff[q] = (w * 256 + q * 64) * 8;
    }

    f32x4 acc[4][4];
    f32x4 zero = {0.f, 0.f, 0.f, 0.f};
    #pragma unroll
    for (int m = 0; m < 4; m++)
        #pragma unroll
        for (int nn = 0; nn < 4; nn++) acc[m][nn] = zero;

    int sw = (lr & 7);
    const char* ab = (const char*)As;
    const char* bb = (const char*)Bs;

    for (int ks = 0; ks < K / 64; ks++) {
        int k0 = ks * 64;
        #pragma unroll
        for (int q = 0; q < 4; q++) {
            stage16(aSrc[q] + k0, As + dOff[q]);
            stage16(bSrc[q] + k0, Bs + dOff[q]);
        }
        __syncthreads();
        #pragma unroll
        for (int kk = 0; kk < 2; kk++) {
            bf16x8 af[4], bf[4];
            #pragma unroll
            for (int m = 0; m < 4; m++) {
                int row = wm * 64 + m * 16 + lr;
                af[m] = *(const bf16x8*)(ab + row * 128 + (((kk * 4 + lk) ^ sw) << 4));
            }
            #pragma unroll
            for (int nn = 0; nn < 4; nn++) {
                int brow = (EPI == 1)
                    ? ((nn & 2) ? 64 : 0) + wn * 32 + (nn & 1) * 16 + lr
                    : wn * 64 + nn * 16 + lr;
                bf[nn] = *(const bf16x8*)(bb + brow * 128 + (((kk * 4 + lk) ^ sw) << 4));
            }
            #pragma unroll
            for (int m = 0; m < 4; m++)
                #pragma unroll
                for (int nn = 0; nn < 4; nn++)
                    acc[m][nn] = __builtin_amdgcn_mfma_f32_16x16x32_bf16(af[m], bf[nn], acc[m][nn], 0, 0, 0);
        }
        __syncthreads();
    }

    #pragma unroll
    for (int m = 0; m < 4; m++) {
        int rb = row0 + wm * 64 + m * 16 + lk * 4;
        if (EPI == 1) {
            #pragma unroll
            for (int nn = 0; nn < 2; nn++) {
                int po = wn * 32 + nn * 16 + lr;          // 0..63 within half
                int cv = h * 64 + po;                     // global v/t column 0..127
                float biv = bias[h * 128 + po];
                float bit = bias[h * 128 + 64 + po];
                #pragma unroll
                for (int j = 0; j < 4; j++) {
                    int r = rb + j;
                    if (r >= n) continue;
                    float win = inrm[r];
                    float won = onrm[r];
                    float ge = bf2f((uint)gid[(size_t)r * 128 + cv]);
                    float tv = acc[m][nn][j] * win + biv + ge;
                    float tt = acc[m][nn + 2][j] * win + bit + ge;
                    float lv = lrelu(tv), lt = lrelu(tt);
                    out[(size_t)r * 384 + 128 + cv] = 0.5f * (lv + lt);
                    uint pk = (uint)f2bf(lv * won) | ((uint)f2bf(lt * won) << 16);
                    *(uint*)&xq[(size_t)r * 384 + 128 + 2 * cv] = pk;
                }
            }
        } else {
            #pragma unroll
            for (int nn = 0; nn < 4; nn++) {
                int cg = wn * 64 + nn * 16 + lr;
                #pragma unroll
                for (int j = 0; j < 4; j++) {
                    int r = rb + j;
                    if (r >= n) continue;
                    xq[(size_t)r * 128 + cg] = f2bf(acc[m][nn][j]);
                }
            }
        }
    }
}

extern "C" void kernel_launch(void* const* d_in, const int* in_sizes, int n_in,
                              void* d_out, int out_size, void* d_ws, size_t ws_size,
                              hipStream_t stream) {
    const float* x      = (const float*)d_in[0];
    const float* id_emb = (const float*)d_in[1];
    const float* Wv0    = (const float*)d_in[2];
    const float* bv0    = (const float*)d_in[3];
    const float* Wv1    = (const float*)d_in[4];
    const float* bv1    = (const float*)d_in[5];
    const float* Wt0    = (const float*)d_in[6];
    const float* bt0    = (const float*)d_in[7];
    const float* Wt1    = (const float*)d_in[8];
    const float* bt1    = (const float*)d_in[9];
    const int*   src    = (const int*)d_in[10];
    const int*   dst    = (const int*)d_in[11];
    const int*   dsti   = (const int*)d_in[12];
    const int E = in_sizes[10];
    const int N = in_sizes[12];
    float* out = (float*)d_out;

    char* p = (char*)d_ws;
    ushort* xn_sc   = (ushort*)p; p += (size_t)N * 128 * 2;
    ushort* qin     = (ushort*)p; p += (size_t)N * 384 * 2;   // [lxn | xhat interleaved]
    ushort* z1      = (ushort*)p; p += (size_t)N * 128 * 2;
    ushort* q       = (ushort*)p; p += (size_t)N * 128 * 2;
    ushort* gid     = (ushort*)p; p += (size_t)N * 128 * 2;
    ushort* W1T     = (ushort*)p; p += 256 * 128 * 2;
    ushort* W2T     = (ushort*)p; p += 128 * 384 * 2;
    float* bias_cat = (float*)p;  p += 256 * 4;
    float* bias2    = (float*)p;  p += 128 * 4;
    float* onrm     = (float*)p;  p += (size_t)N * 4;
    float* inrm     = (float*)p;  p += (size_t)N * 4;
    int* deg_out    = (int*)p;    p += (size_t)N * 4;
    int* deg_in     = (int*)p;    p += (size_t)N * 4;
    int* cursor     = (int*)p;    p += (size_t)N * 4;
    int* row_ptr    = (int*)p;    p += (size_t)(N + 1) * 4;
    int* csum       = (int*)p;    p += 1024 * 4;
    int* col        = (int*)p;    p += (size_t)E * 4;

    hipMemsetAsync(deg_out, 0, (size_t)N * 3 * 4, stream);   // deg_out|deg_in|cursor contiguous

    int be = (E + 255) / 256;
    int bn = (N + 255) / 256;
    int bw = (N * 64 + 255) / 256;          // one wave per row
    int bg = (N + 127) / 128;               // 128-row GEMM tiles
    int nb = (N + 1023) / 1024;             // scan chunks

    k_degrees<<<be, 256, 0, stream>>>(src, dst, deg_out, deg_in, E);
    k_norms  <<<bn, 256, 0, stream>>>(deg_out, deg_in, onrm, inrm, N);
    k_scan1  <<<nb, 1024, 0, stream>>>(deg_in, row_ptr, csum, N);
    k_scan2  <<<1, 1024, 0, stream>>>(csum, nb);
    k_scan3  <<<bn, 256, 0, stream>>>(row_ptr, csum, N);
    k_fill   <<<be, 256, 0, stream>>>(src, dst, row_ptr, cursor, col, E);
    k_wprep  <<<192, 256, 0, stream>>>(Wv0, Wt0, Wv1, Wt1, bv0, bt0, bv1, bt1,
                                       W1T, W2T, bias_cat, bias2);
    k_normx  <<<bw, 256, 0, stream>>>(x, onrm, dsti, id_emb, xn_sc, qin, gid, out, N);

    k_agg1<<<bw, 256, 0, stream>>>(xn_sc, row_ptr, col, z1, N);
    k_gemm<128, 128, 1><<<dim3(bg, 2), 256, 0, stream>>>(
        z1, W1T, inrm, onrm, gid, bias_cat, qin, out, N);
    k_gemm<384, 384, 3><<<dim3(bg, 1), 256, 0, stream>>>(
        qin, W2T, inrm, onrm, gid, bias2, q, out, N);
    k_agg2e<<<bw, 256, 0, stream>>>(q, row_ptr, col, inrm, bias2, gid, out, N);
}

// Round 12
// 292.488 us; speedup vs baseline: 1.3868x; 1.1286x over previous
//
#include <hip/hip_runtime.h>
#include <math.h>

// MMGCN: both GEMMs pushed through the (linear) aggregations.
//   z1 = A.(xn*onrm)                                -> conv1 GEMM K=128 (shared v,t)
//   qin = [leaky(xn*onrm) | leaky(xhat*onrm) interleaved]  (per node, bf16)
//   q   = qin @ W2  (K=384 GEMM, PRE-aggregation)   -> conv2 gathers 128-wide q
//   out256 = agg(q)*in_norm + 0.5(b1v+b1t) + gid    (fused into the gather)
// GEMMs: m97 structure — 128x128 tile, BK=64, global_load_lds (16B DMA), XOR swizzle.
// Gathers: 16-lane row-groups (4 rows/wave) -> 4 independent edge chains per wave,
// unroll-2 -> 8 outstanding row fetches/wave (was 2 with one 64-lane row per wave).

typedef unsigned int uint;
typedef unsigned short ushort;
using bf16x8 = __attribute__((ext_vector_type(8))) short;
using f32x4  = __attribute__((ext_vector_type(4))) float;

__device__ __forceinline__ float lrelu(float v) { return v >= 0.0f ? v : 0.01f * v; }
__device__ __forceinline__ float bf2f(uint us) { return __uint_as_float(us << 16); }
__device__ __forceinline__ ushort f2bf(float f) {
    uint u = __float_as_uint(f);
    u += 0x7fffu + ((u >> 16) & 1u);   // round-to-nearest-even
    return (ushort)(u >> 16);
}
__device__ __forceinline__ void stage16(const ushort* g, ushort* l) {
    __builtin_amdgcn_global_load_lds(
        (const __attribute__((address_space(1))) void*)(g),
        (__attribute__((address_space(3))) void*)(l), 16, 0, 0);
}

// ---------------- degree histograms ----------------
__global__ void k_degrees(const int* __restrict__ src, const int* __restrict__ dst,
                          int* __restrict__ deg_out, int* __restrict__ deg_in, int E) {
    int e = blockIdx.x * blockDim.x + threadIdx.x;
    if (e < E) {
        atomicAdd(&deg_out[src[e]], 1);
        atomicAdd(&deg_in[dst[e]], 1);
    }
}

// ---------------- scan1 (+ norms fused): per-1024-chunk inclusive scan of deg_in ------
__global__ void k_scan1(const int* __restrict__ deg_out, const int* __restrict__ deg_in,
                        int* __restrict__ row_ptr, int* __restrict__ csum,
                        float* __restrict__ onrm, float* __restrict__ inrm, int n) {
    __shared__ int wsum[16];
    __shared__ int wpre[16];
    int lane = threadIdx.x & 63;
    int wid  = threadIdx.x >> 6;
    int i = blockIdx.x * 1024 + threadIdx.x;
    int v = (i < n) ? deg_in[i] : 0;
    if (i < n) {
        onrm[i] = 1.0f / sqrtf((float)max(deg_out[i], 1));
        inrm[i] = 1.0f / sqrtf((float)max(v, 1));
    }
    int s = v;
    #pragma unroll
    for (int off = 1; off < 64; off <<= 1) {
        int t = __shfl_up(s, off, 64);
        if (lane >= off) s += t;
    }
    if (lane == 63) wsum[wid] = s;
    __syncthreads();
    if (wid == 0) {
        int wv = (lane < 16) ? wsum[lane] : 0;
        int ss = wv;
        #pragma unroll
        for (int off = 1; off < 16; off <<= 1) {
            int t = __shfl_up(ss, off, 64);
            if (lane >= off) ss += t;
        }
        if (lane < 16) wpre[lane] = ss - wv;
    }
    __syncthreads();
    int incl = s + wpre[wid];
    if (i < n) row_ptr[i + 1] = incl;                        // chunk-local for now
    if (threadIdx.x == 1023) csum[blockIdx.x] = incl;        // chunk total
}

__global__ void k_scan2(int* __restrict__ csum, int nb) {
    __shared__ int wsum[16];
    __shared__ int wpre[16];
    int lane = threadIdx.x & 63;
    int wid  = threadIdx.x >> 6;
    int i = threadIdx.x;
    int v = (i < nb) ? csum[i] : 0;
    int s = v;
    #pragma unroll
    for (int off = 1; off < 64; off <<= 1) {
        int t = __shfl_up(s, off, 64);
        if (lane >= off) s += t;
    }
    if (lane == 63) wsum[wid] = s;
    __syncthreads();
    if (wid == 0) {
        int wv = (lane < 16) ? wsum[lane] : 0;
        int ss = wv;
        #pragma unroll
        for (int off = 1; off < 16; off <<= 1) {
            int t = __shfl_up(ss, off, 64);
            if (lane >= off) ss += t;
        }
        if (lane < 16) wpre[lane] = ss - wv;
    }
    __syncthreads();
    if (i < nb) csum[i] = s + wpre[wid];
}

__global__ void k_scan3(int* __restrict__ row_ptr, const int* __restrict__ csum, int n) {
    int i = blockIdx.x * blockDim.x + threadIdx.x;
    if (i == 0) row_ptr[0] = 0;
    if (i < n) {
        int b = i >> 10;
        if (b > 0) row_ptr[i + 1] += csum[b - 1];
    }
}

__global__ void k_fill(const int* __restrict__ src, const int* __restrict__ dst,
                       const int* __restrict__ row_ptr, int* __restrict__ cursor,
                       int* __restrict__ col, int E) {
    int e = blockIdx.x * blockDim.x + threadIdx.x;
    if (e < E) {
        int d = dst[e];
        int pos = atomicAdd(&cursor[d], 1);
        col[row_ptr[d] + pos] = src[e];
    }
}

// ---------------- weight prep ----------------
// W1T [256 rows][128 k]: row h*128+p: p<64 -> Wv0 col (h*64+p); p>=64 -> Wt0 col (h*64+p-64)
// W2T [128 rows][384 k]: k 0:128 = 0.5(Wv1+Wt1); k 128+2q+b = 0.5 Wb1[128+q]  (interleaved)
__global__ void k_wprep(const float* __restrict__ Wv0, const float* __restrict__ Wt0,
                        const float* __restrict__ Wv1, const float* __restrict__ Wt1,
                        const float* __restrict__ bv0, const float* __restrict__ bt0,
                        const float* __restrict__ bv1, const float* __restrict__ bt1,
                        ushort* __restrict__ W1T, ushort* __restrict__ W2T,
                        float* __restrict__ bias_cat, float* __restrict__ bias2) {
    int t = blockIdx.x * blockDim.x + threadIdx.x;
    if (t < 256 * 128) {
        int cp = t >> 7, k = t & 127;
        int p = cp & 127;
        int col = ((cp >> 7) << 6) + (p & 63);
        float v = (p < 64) ? Wv0[k * 128 + col] : Wt0[k * 128 + col];
        W1T[cp * 128 + k] = f2bf(v);
    }
    if (t < 128 * 384) {
        int c = t / 384, r = t % 384;
        float v;
        if (r < 128) v = 0.5f * (Wv1[r * 128 + c] + Wt1[r * 128 + c]);
        else {
            int q = (r - 128) >> 1;
            v = 0.5f * (((r - 128) & 1) ? Wt1[(128 + q) * 128 + c] : Wv1[(128 + q) * 128 + c]);
        }
        W2T[c * 384 + r] = f2bf(v);
    }
    if (t < 256) {
        int p = t & 127;
        int col = ((t >> 7) << 6) + (p & 63);
        bias_cat[t] = (p < 64) ? bv0[col] : bt0[col];
    }
    if (t < 128) bias2[t] = 0.5f * (bv1[t] + bt1[t]);
}

// --- row L2-normalize x; out[:,0:128]=leaky(xn); xn_sc=xn*onrm; qin[:,0:128]=leaky(xn_sc);
//     gid = id_emb[dst_ids] densified (bf16) ---
__global__ void k_normx(const float* __restrict__ x, const float* __restrict__ onrm,
                        const int* __restrict__ dsti, const float* __restrict__ id_emb,
                        ushort* __restrict__ xn_sc, ushort* __restrict__ qin,
                        ushort* __restrict__ gid, float* __restrict__ out, int n) {
    int gtid = blockIdx.x * blockDim.x + threadIdx.x;
    int row  = gtid >> 6;
    int lane = gtid & 63;
    if (row >= n) return;
    int c = lane * 2;
    float2 v = *(const float2*)&x[(size_t)row * 128 + c];
    float s = v.x * v.x + v.y * v.y;
    #pragma unroll
    for (int off = 1; off < 64; off <<= 1) s += __shfl_xor(s, off, 64);
    float scale = 1.0f / fmaxf(sqrtf(s), 1e-12f);
    float nx = v.x * scale, ny = v.y * scale;
    *(float2*)&out[(size_t)row * 384 + c] = make_float2(lrelu(nx), lrelu(ny));
    float so = onrm[row];
    float sx = nx * so, sy = ny * so;
    *(uint*)&xn_sc[(size_t)row * 128 + c] = (uint)f2bf(sx) | ((uint)f2bf(sy) << 16);
    *(uint*)&qin[(size_t)row * 384 + c] = (uint)f2bf(lrelu(sx)) | ((uint)f2bf(lrelu(sy)) << 16);
    int g = dsti[row];
    float2 ge = *(const float2*)&id_emb[(size_t)g * 128 + c];
    *(uint*)&gid[(size_t)row * 128 + c] = (uint)f2bf(ge.x) | ((uint)f2bf(ge.y) << 16);
}

// ------- gather pass 1: z1 = A.xn_sc  (16-lane groups, 4 rows/wave, unroll-2) -------
__global__ void k_agg1(const ushort* __restrict__ xn_sc, const int* __restrict__ rp,
                       const int* __restrict__ col, ushort* __restrict__ z1, int n) {
    int gtid = blockIdx.x * blockDim.x + threadIdx.x;
    int row  = gtid >> 4;
    int lane = gtid & 15;
    if (row >= n) return;
    int c = lane * 8;                            // 8 bf16 = 16B per lane
    float a0 = 0.f, a1 = 0.f, a2 = 0.f, a3 = 0.f, a4 = 0.f, a5 = 0.f, a6 = 0.f, a7 = 0.f;
    int e0 = rp[row], e1 = rp[row + 1];
    int e = e0;
    for (; e + 1 < e1; e += 2) {
        int s0 = col[e], s1 = col[e + 1];
        uint4 v0 = *(const uint4*)&xn_sc[(size_t)s0 * 128 + c];
        uint4 v1 = *(const uint4*)&xn_sc[(size_t)s1 * 128 + c];
        a0 += bf2f(v0.x & 0xffffu) + bf2f(v1.x & 0xffffu);
        a1 += bf2f(v0.x >> 16)     + bf2f(v1.x >> 16);
        a2 += bf2f(v0.y & 0xffffu) + bf2f(v1.y & 0xffffu);
        a3 += bf2f(v0.y >> 16)     + bf2f(v1.y >> 16);
        a4 += bf2f(v0.z & 0xffffu) + bf2f(v1.z & 0xffffu);
        a5 += bf2f(v0.z >> 16)     + bf2f(v1.z >> 16);
        a6 += bf2f(v0.w & 0xffffu) + bf2f(v1.w & 0xffffu);
        a7 += bf2f(v0.w >> 16)     + bf2f(v1.w >> 16);
    }
    if (e < e1) {
        uint4 v0 = *(const uint4*)&xn_sc[(size_t)col[e] * 128 + c];
        a0 += bf2f(v0.x & 0xffffu); a1 += bf2f(v0.x >> 16);
        a2 += bf2f(v0.y & 0xffffu); a3 += bf2f(v0.y >> 16);
        a4 += bf2f(v0.z & 0xffffu); a5 += bf2f(v0.z >> 16);
        a6 += bf2f(v0.w & 0xffffu); a7 += bf2f(v0.w >> 16);
    }
    uint4 p;
    p.x = (uint)f2bf(a0) | ((uint)f2bf(a1) << 16);
    p.y = (uint)f2bf(a2) | ((uint)f2bf(a3) << 16);
    p.z = (uint)f2bf(a4) | ((uint)f2bf(a5) << 16);
    p.w = (uint)f2bf(a6) | ((uint)f2bf(a7) << 16);
    *(uint4*)&z1[(size_t)row * 128 + c] = p;
}

// --- gather pass 2 + conv2 epilogue (16-lane groups): out[:,256:384] = agg(q)*w+b+gid ---
__global__ void k_agg2e(const ushort* __restrict__ q, const int* __restrict__ rp,
                        const int* __restrict__ col, const float* __restrict__ inrm,
                        const float* __restrict__ bias2, const ushort* __restrict__ gid,
                        float* __restrict__ out, int n) {
    int gtid = blockIdx.x * blockDim.x + threadIdx.x;
    int row  = gtid >> 4;
    int lane = gtid & 15;
    if (row >= n) return;
    int c = lane * 8;
    float a0 = 0.f, a1 = 0.f, a2 = 0.f, a3 = 0.f, a4 = 0.f, a5 = 0.f, a6 = 0.f, a7 = 0.f;
    int e0 = rp[row], e1 = rp[row + 1];
    int e = e0;
    for (; e + 1 < e1; e += 2) {
        int s0 = col[e], s1 = col[e + 1];
        uint4 v0 = *(const uint4*)&q[(size_t)s0 * 128 + c];
        uint4 v1 = *(const uint4*)&q[(size_t)s1 * 128 + c];
        a0 += bf2f(v0.x & 0xffffu) + bf2f(v1.x & 0xffffu);
        a1 += bf2f(v0.x >> 16)     + bf2f(v1.x >> 16);
        a2 += bf2f(v0.y & 0xffffu) + bf2f(v1.y & 0xffffu);
        a3 += bf2f(v0.y >> 16)     + bf2f(v1.y >> 16);
        a4 += bf2f(v0.z & 0xffffu) + bf2f(v1.z & 0xffffu);
        a5 += bf2f(v0.z >> 16)     + bf2f(v1.z >> 16);
        a6 += bf2f(v0.w & 0xffffu) + bf2f(v1.w & 0xffffu);
        a7 += bf2f(v0.w >> 16)     + bf2f(v1.w >> 16);
    }
    if (e < e1) {
        uint4 v0 = *(const uint4*)&q[(size_t)col[e] * 128 + c];
        a0 += bf2f(v0.x & 0xffffu); a1 += bf2f(v0.x >> 16);
        a2 += bf2f(v0.y & 0xffffu); a3 += bf2f(v0.y >> 16);
        a4 += bf2f(v0.z & 0xffffu); a5 += bf2f(v0.z >> 16);
        a6 += bf2f(v0.w & 0xffffu); a7 += bf2f(v0.w >> 16);
    }
    float win = inrm[row];
    float4 b0 = *(const float4*)&bias2[c];
    float4 b1 = *(const float4*)&bias2[c + 4];
    uint4 pg = *(const uint4*)&gid[(size_t)row * 128 + c];
    float4 o0, o1;
    o0.x = a0 * win + b0.x + bf2f(pg.x & 0xffffu);
    o0.y = a1 * win + b0.y + bf2f(pg.x >> 16);
    o0.z = a2 * win + b0.z + bf2f(pg.y & 0xffffu);
    o0.w = a3 * win + b0.w + bf2f(pg.y >> 16);
    o1.x = a4 * win + b1.x + bf2f(pg.z & 0xffffu);
    o1.y = a5 * win + b1.y + bf2f(pg.z >> 16);
    o1.z = a6 * win + b1.z + bf2f(pg.w & 0xffffu);
    o1.w = a7 * win + b1.w + bf2f(pg.w >> 16);
    *(float4*)&out[(size_t)row * 384 + 256 + c]     = o0;
    *(float4*)&out[(size_t)row * 384 + 256 + c + 4] = o1;
}

// ---- m97-style MFMA GEMM: 128 rows x 128 cols, BK=64, global_load_lds + XOR swizzle ----
// EPI==1 (conv1, grid.y=h): cols = W1T rows [h*128,h*128+128). Epilogue fuses conv1 output
//   and qin[:,128:384] (interleaved). EPI==3 (gemm_q): q = A @ W2 (bf16 out).
template<int K, int LDA, int EPI>
__global__ __launch_bounds__(256) void k_gemm(
    const ushort* __restrict__ A, const ushort* __restrict__ WT,
    const float* __restrict__ inrm, const float* __restrict__ onrm,
    const ushort* __restrict__ gid, const float* __restrict__ bias,
    ushort* __restrict__ xq, float* __restrict__ out, int n)
{
    __shared__ __align__(16) ushort As[128 * 64];
    __shared__ __align__(16) ushort Bs[128 * 64];
    int tid  = threadIdx.x;
    int lane = tid & 63;
    int w    = tid >> 6;
    int wm   = w >> 1, wn = w & 1;
    int lr   = lane & 15, lk = lane >> 4;
    int row0 = blockIdx.x * 128;
    int h    = blockIdx.y;
    int cb   = h * 128;

    const ushort* aSrc[4]; const ushort* bSrc[4]; int dOff[4];
    #pragma unroll
    for (int q = 0; q < 4; q++) {
        int g = w * 256 + q * 64 + lane;
        int row = g >> 3, lc = g & 7;
        int scol = ((lc ^ (row & 7)) << 3);
        aSrc[q] = A  + (size_t)(row0 + row) * LDA + scol;
        bSrc[q] = WT + (size_t)(cb + row) * K + scol;
        dOff[q] = (w * 256 + q * 64) * 8;
    }

    f32x4 acc[4][4];
    f32x4 zero = {0.f, 0.f, 0.f, 0.f};
    #pragma unroll
    for (int m = 0; m < 4; m++)
        #pragma unroll
        for (int nn = 0; nn < 4; nn++) acc[m][nn] = zero;

    int sw = (lr & 7);
    const char* ab = (const char*)As;
    const char* bb = (const char*)Bs;

    for (int ks = 0; ks < K / 64; ks++) {
        int k0 = ks * 64;
        #pragma unroll
        for (int q = 0; q < 4; q++) {
            stage16(aSrc[q] + k0, As + dOff[q]);
            stage16(bSrc[q] + k0, Bs + dOff[q]);
        }
        __syncthreads();
        #pragma unroll
        for (int kk = 0; kk < 2; kk++) {
            bf16x8 af[4], bf[4];
            #pragma unroll
            for (int m = 0; m < 4; m++) {
                int row = wm * 64 + m * 16 + lr;
                af[m] = *(const bf16x8*)(ab + row * 128 + (((kk * 4 + lk) ^ sw) << 4));
            }
            #pragma unroll
            for (int nn = 0; nn < 4; nn++) {
                int brow = (EPI == 1)
                    ? ((nn & 2) ? 64 : 0) + wn * 32 + (nn & 1) * 16 + lr
                    : wn * 64 + nn * 16 + lr;
                bf[nn] = *(const bf16x8*)(bb + brow * 128 + (((kk * 4 + lk) ^ sw) << 4));
            }
            #pragma unroll
            for (int m = 0; m < 4; m++)
                #pragma unroll
                for (int nn = 0; nn < 4; nn++)
                    acc[m][nn] = __builtin_amdgcn_mfma_f32_16x16x32_bf16(af[m], bf[nn], acc[m][nn], 0, 0, 0);
        }
        __syncthreads();
    }

    #pragma unroll
    for (int m = 0; m < 4; m++) {
        int rb = row0 + wm * 64 + m * 16 + lk * 4;
        if (EPI == 1) {
            #pragma unroll
            for (int nn = 0; nn < 2; nn++) {
                int po = wn * 32 + nn * 16 + lr;
                int cv = h * 64 + po;
                float biv = bias[h * 128 + po];
                float bit = bias[h * 128 + 64 + po];
                #pragma unroll
                for (int j = 0; j < 4; j++) {
                    int r = rb + j;
                    if (r >= n) continue;
                    float win = inrm[r];
                    float won = onrm[r];
                    float ge = bf2f((uint)gid[(size_t)r * 128 + cv]);
                    float tv = acc[m][nn][j] * win + biv + ge;
                    float tt = acc[m][nn + 2][j] * win + bit + ge;
                    float lv = lrelu(tv), lt = lrelu(tt);
                    out[(size_t)r * 384 + 128 + cv] = 0.5f * (lv + lt);
                    uint pk = (uint)f2bf(lv * won) | ((uint)f2bf(lt * won) << 16);
                    *(uint*)&xq[(size_t)r * 384 + 128 + 2 * cv] = pk;
                }
            }
        } else {
            #pragma unroll
            for (int nn = 0; nn < 4; nn++) {
                int cg = wn * 64 + nn * 16 + lr;
                #pragma unroll
                for (int j = 0; j < 4; j++) {
                    int r = rb + j;
                    if (r >= n) continue;
                    xq[(size_t)r * 128 + cg] = f2bf(acc[m][nn][j]);
                }
            }
        }
    }
}

extern "C" void kernel_launch(void* const* d_in, const int* in_sizes, int n_in,
                              void* d_out, int out_size, void* d_ws, size_t ws_size,
                              hipStream_t stream) {
    const float* x      = (const float*)d_in[0];
    const float* id_emb = (const float*)d_in[1];
    const float* Wv0    = (const float*)d_in[2];
    const float* bv0    = (const float*)d_in[3];
    const float* Wv1    = (const float*)d_in[4];
    const float* bv1    = (const float*)d_in[5];
    const float* Wt0    = (const float*)d_in[6];
    const float* bt0    = (const float*)d_in[7];
    const float* Wt1    = (const float*)d_in[8];
    const float* bt1    = (const float*)d_in[9];
    const int*   src    = (const int*)d_in[10];
    const int*   dst    = (const int*)d_in[11];
    const int*   dsti   = (const int*)d_in[12];
    const int E = in_sizes[10];
    const int N = in_sizes[12];
    float* out = (float*)d_out;

    char* p = (char*)d_ws;
    ushort* xn_sc   = (ushort*)p; p += (size_t)N * 128 * 2;
    ushort* qin     = (ushort*)p; p += (size_t)N * 384 * 2;   // [lxn | xhat interleaved]
    ushort* z1      = (ushort*)p; p += (size_t)N * 128 * 2;
    ushort* q       = (ushort*)p; p += (size_t)N * 128 * 2;
    ushort* gid     = (ushort*)p; p += (size_t)N * 128 * 2;
    ushort* W1T     = (ushort*)p; p += 256 * 128 * 2;
    ushort* W2T     = (ushort*)p; p += 128 * 384 * 2;
    float* bias_cat = (float*)p;  p += 256 * 4;
    float* bias2    = (float*)p;  p += 128 * 4;
    float* onrm     = (float*)p;  p += (size_t)N * 4;
    float* inrm     = (float*)p;  p += (size_t)N * 4;
    int* deg_out    = (int*)p;    p += (size_t)N * 4;
    int* deg_in     = (int*)p;    p += (size_t)N * 4;
    int* cursor     = (int*)p;    p += (size_t)N * 4;
    int* row_ptr    = (int*)p;    p += (size_t)(N + 1) * 4;
    int* csum       = (int*)p;    p += 1024 * 4;
    int* col        = (int*)p;    p += (size_t)E * 4;

    hipMemsetAsync(deg_out, 0, (size_t)N * 3 * 4, stream);   // deg_out|deg_in|cursor contiguous

    int be = (E + 255) / 256;
    int bn = (N + 255) / 256;
    int bw = (N * 64 + 255) / 256;          // one wave per row (normx)
    int bq = (N * 16 + 255) / 256;          // 16-lane groups (gathers)
    int bg = (N + 127) / 128;               // 128-row GEMM tiles
    int nb = (N + 1023) / 1024;             // scan chunks

    k_degrees<<<be, 256, 0, stream>>>(src, dst, deg_out, deg_in, E);
    k_scan1  <<<nb, 1024, 0, stream>>>(deg_out, deg_in, row_ptr, csum, onrm, inrm, N);
    k_scan2  <<<1, 1024, 0, stream>>>(csum, nb);
    k_scan3  <<<bn, 256, 0, stream>>>(row_ptr, csum, N);
    k_fill   <<<be, 256, 0, stream>>>(src, dst, row_ptr, cursor, col, E);
    k_wprep  <<<192, 256, 0, stream>>>(Wv0, Wt0, Wv1, Wt1, bv0, bt0, bv1, bt1,
                                       W1T, W2T, bias_cat, bias2);
    k_normx  <<<bw, 256, 0, stream>>>(x, onrm, dsti, id_emb, xn_sc, qin, gid, out, N);

    k_agg1<<<bq, 256, 0, stream>>>(xn_sc, row_ptr, col, z1, N);
    k_gemm<128, 128, 1><<<dim3(bg, 2), 256, 0, stream>>>(
        z1, W1T, inrm, onrm, gid, bias_cat, qin, out, N);
    k_gemm<384, 384, 3><<<dim3(bg, 1), 256, 0, stream>>>(
        qin, W2T, inrm, onrm, gid, bias2, q, out, N);
    k_agg2e<<<bq, 256, 0, stream>>>(q, row_ptr, col, inrm, bias2, gid, out, N);
}

// Round 13
// 287.664 us; speedup vs baseline: 1.4101x; 1.0168x over previous
//
#include <hip/hip_runtime.h>
#include <math.h>

// MMGCN: both GEMMs pushed through the (linear) aggregations.
//   z1 = A.(xn*onrm)                                -> conv1 GEMM K=128 (shared v,t)
//   qin = [leaky(xn*onrm) | leaky(xhat*onrm) interleaved]  (per node, bf16)
//   q   = qin @ W2  (K=384 GEMM, PRE-aggregation)   -> conv2 gathers 128-wide q
//   out256 = agg(q)*in_norm + 0.5(b1v+b1t) + gid    (fused into the gather)
// GEMMs: m97 structure — 128x128 tile, BK=64, global_load_lds (16B DMA), XOR swizzle.
// Gathers + normx: 16-lane row-groups (4 rows/wave), gather unroll-4 -> up to 16
// independent row fetches in flight per wave (latency-chain MLP, the round-12 lever).

typedef unsigned int uint;
typedef unsigned short ushort;
using bf16x8 = __attribute__((ext_vector_type(8))) short;
using f32x4  = __attribute__((ext_vector_type(4))) float;

__device__ __forceinline__ float lrelu(float v) { return v >= 0.0f ? v : 0.01f * v; }
__device__ __forceinline__ float bf2f(uint us) { return __uint_as_float(us << 16); }
__device__ __forceinline__ ushort f2bf(float f) {
    uint u = __float_as_uint(f);
    u += 0x7fffu + ((u >> 16) & 1u);   // round-to-nearest-even
    return (ushort)(u >> 16);
}
__device__ __forceinline__ void stage16(const ushort* g, ushort* l) {
    __builtin_amdgcn_global_load_lds(
        (const __attribute__((address_space(1))) void*)(g),
        (__attribute__((address_space(3))) void*)(l), 16, 0, 0);
}
__device__ __forceinline__ void acc8(uint4 v, float* a) {
    a[0] += bf2f(v.x & 0xffffu); a[1] += bf2f(v.x >> 16);
    a[2] += bf2f(v.y & 0xffffu); a[3] += bf2f(v.y >> 16);
    a[4] += bf2f(v.z & 0xffffu); a[5] += bf2f(v.z >> 16);
    a[6] += bf2f(v.w & 0xffffu); a[7] += bf2f(v.w >> 16);
}

// ---------------- degree histograms ----------------
__global__ void k_degrees(const int* __restrict__ src, const int* __restrict__ dst,
                          int* __restrict__ deg_out, int* __restrict__ deg_in, int E) {
    int e = blockIdx.x * blockDim.x + threadIdx.x;
    if (e < E) {
        atomicAdd(&deg_out[src[e]], 1);
        atomicAdd(&deg_in[dst[e]], 1);
    }
}

// ---------------- scan1 (+ norms fused): per-1024-chunk inclusive scan of deg_in ------
__global__ void k_scan1(const int* __restrict__ deg_out, const int* __restrict__ deg_in,
                        int* __restrict__ row_ptr, int* __restrict__ csum,
                        float* __restrict__ onrm, float* __restrict__ inrm, int n) {
    __shared__ int wsum[16];
    __shared__ int wpre[16];
    int lane = threadIdx.x & 63;
    int wid  = threadIdx.x >> 6;
    int i = blockIdx.x * 1024 + threadIdx.x;
    int v = (i < n) ? deg_in[i] : 0;
    if (i < n) {
        onrm[i] = 1.0f / sqrtf((float)max(deg_out[i], 1));
        inrm[i] = 1.0f / sqrtf((float)max(v, 1));
    }
    int s = v;
    #pragma unroll
    for (int off = 1; off < 64; off <<= 1) {
        int t = __shfl_up(s, off, 64);
        if (lane >= off) s += t;
    }
    if (lane == 63) wsum[wid] = s;
    __syncthreads();
    if (wid == 0) {
        int wv = (lane < 16) ? wsum[lane] : 0;
        int ss = wv;
        #pragma unroll
        for (int off = 1; off < 16; off <<= 1) {
            int t = __shfl_up(ss, off, 64);
            if (lane >= off) ss += t;
        }
        if (lane < 16) wpre[lane] = ss - wv;
    }
    __syncthreads();
    int incl = s + wpre[wid];
    if (i < n) row_ptr[i + 1] = incl;                        // chunk-local for now
    if (threadIdx.x == 1023) csum[blockIdx.x] = incl;        // chunk total
}

__global__ void k_scan2(int* __restrict__ csum, int nb) {
    __shared__ int wsum[16];
    __shared__ int wpre[16];
    int lane = threadIdx.x & 63;
    int wid  = threadIdx.x >> 6;
    int i = threadIdx.x;
    int v = (i < nb) ? csum[i] : 0;
    int s = v;
    #pragma unroll
    for (int off = 1; off < 64; off <<= 1) {
        int t = __shfl_up(s, off, 64);
        if (lane >= off) s += t;
    }
    if (lane == 63) wsum[wid] = s;
    __syncthreads();
    if (wid == 0) {
        int wv = (lane < 16) ? wsum[lane] : 0;
        int ss = wv;
        #pragma unroll
        for (int off = 1; off < 16; off <<= 1) {
            int t = __shfl_up(ss, off, 64);
            if (lane >= off) ss += t;
        }
        if (lane < 16) wpre[lane] = ss - wv;
    }
    __syncthreads();
    if (i < nb) csum[i] = s + wpre[wid];
}

// scan3: finalize row_ptr and materialize cursor = row_ptr (absolute fill cursors)
__global__ void k_scan3(int* __restrict__ row_ptr, const int* __restrict__ csum,
                        int* __restrict__ cursor, int n) {
    int i = blockIdx.x * blockDim.x + threadIdx.x;
    if (i == 0) { row_ptr[0] = 0; cursor[0] = 0; }
    if (i < n) {
        int b = i >> 10;
        int rv = row_ptr[i + 1] + ((b > 0) ? csum[b - 1] : 0);
        row_ptr[i + 1] = rv;
        if (i + 1 < n) cursor[i + 1] = rv;
    }
}

__global__ void k_fill(const int* __restrict__ src, const int* __restrict__ dst,
                       int* __restrict__ cursor, int* __restrict__ col, int E) {
    int e = blockIdx.x * blockDim.x + threadIdx.x;
    if (e < E) {
        int pos = atomicAdd(&cursor[dst[e]], 1);
        col[pos] = src[e];
    }
}

// ---------------- weight prep ----------------
// W1T [256 rows][128 k]: row h*128+p: p<64 -> Wv0 col (h*64+p); p>=64 -> Wt0 col (h*64+p-64)
// W2T [128 rows][384 k]: k 0:128 = 0.5(Wv1+Wt1); k 128+2q+b = 0.5 Wb1[128+q]  (interleaved)
__global__ void k_wprep(const float* __restrict__ Wv0, const float* __restrict__ Wt0,
                        const float* __restrict__ Wv1, const float* __restrict__ Wt1,
                        const float* __restrict__ bv0, const float* __restrict__ bt0,
                        const float* __restrict__ bv1, const float* __restrict__ bt1,
                        ushort* __restrict__ W1T, ushort* __restrict__ W2T,
                        float* __restrict__ bias_cat, float* __restrict__ bias2) {
    int t = blockIdx.x * blockDim.x + threadIdx.x;
    if (t < 256 * 128) {
        int cp = t >> 7, k = t & 127;
        int p = cp & 127;
        int col = ((cp >> 7) << 6) + (p & 63);
        float v = (p < 64) ? Wv0[k * 128 + col] : Wt0[k * 128 + col];
        W1T[cp * 128 + k] = f2bf(v);
    }
    if (t < 128 * 384) {
        int c = t / 384, r = t % 384;
        float v;
        if (r < 128) v = 0.5f * (Wv1[r * 128 + c] + Wt1[r * 128 + c]);
        else {
            int q = (r - 128) >> 1;
            v = 0.5f * (((r - 128) & 1) ? Wt1[(128 + q) * 128 + c] : Wv1[(128 + q) * 128 + c]);
        }
        W2T[c * 384 + r] = f2bf(v);
    }
    if (t < 256) {
        int p = t & 127;
        int col = ((t >> 7) << 6) + (p & 63);
        bias_cat[t] = (p < 64) ? bv0[col] : bt0[col];
    }
    if (t < 128) bias2[t] = 0.5f * (bv1[t] + bt1[t]);
}

// --- row L2-normalize x (16-lane groups, 4 rows/wave for id_emb gather MLP);
//     out[:,0:128]=leaky(xn); xn_sc=xn*onrm; qin[:,0:128]=leaky(xn_sc); gid bf16 ---
__global__ void k_normx(const float* __restrict__ x, const float* __restrict__ onrm,
                        const int* __restrict__ dsti, const float* __restrict__ id_emb,
                        ushort* __restrict__ xn_sc, ushort* __restrict__ qin,
                        ushort* __restrict__ gid, float* __restrict__ out, int n) {
    int gtid = blockIdx.x * blockDim.x + threadIdx.x;
    int row  = gtid >> 4;
    int lane = gtid & 15;
    if (row >= n) return;
    int c = lane * 8;
    float4 v0 = *(const float4*)&x[(size_t)row * 128 + c];
    float4 v1 = *(const float4*)&x[(size_t)row * 128 + c + 4];
    float s = v0.x * v0.x + v0.y * v0.y + v0.z * v0.z + v0.w * v0.w
            + v1.x * v1.x + v1.y * v1.y + v1.z * v1.z + v1.w * v1.w;
    #pragma unroll
    for (int off = 1; off < 16; off <<= 1) s += __shfl_xor(s, off, 64);
    float scale = 1.0f / fmaxf(sqrtf(s), 1e-12f);
    float nx[8] = {v0.x * scale, v0.y * scale, v0.z * scale, v0.w * scale,
                   v1.x * scale, v1.y * scale, v1.z * scale, v1.w * scale};
    *(float4*)&out[(size_t)row * 384 + c] =
        make_float4(lrelu(nx[0]), lrelu(nx[1]), lrelu(nx[2]), lrelu(nx[3]));
    *(float4*)&out[(size_t)row * 384 + c + 4] =
        make_float4(lrelu(nx[4]), lrelu(nx[5]), lrelu(nx[6]), lrelu(nx[7]));
    float so = onrm[row];
    float sx[8];
    #pragma unroll
    for (int j = 0; j < 8; j++) sx[j] = nx[j] * so;
    uint4 px = make_uint4((uint)f2bf(sx[0]) | ((uint)f2bf(sx[1]) << 16),
                          (uint)f2bf(sx[2]) | ((uint)f2bf(sx[3]) << 16),
                          (uint)f2bf(sx[4]) | ((uint)f2bf(sx[5]) << 16),
                          (uint)f2bf(sx[6]) | ((uint)f2bf(sx[7]) << 16));
    *(uint4*)&xn_sc[(size_t)row * 128 + c] = px;
    uint4 pq = make_uint4((uint)f2bf(lrelu(sx[0])) | ((uint)f2bf(lrelu(sx[1])) << 16),
                          (uint)f2bf(lrelu(sx[2])) | ((uint)f2bf(lrelu(sx[3])) << 16),
                          (uint)f2bf(lrelu(sx[4])) | ((uint)f2bf(lrelu(sx[5])) << 16),
                          (uint)f2bf(lrelu(sx[6])) | ((uint)f2bf(lrelu(sx[7])) << 16));
    *(uint4*)&qin[(size_t)row * 384 + c] = pq;
    int g = dsti[row];
    float4 g0 = *(const float4*)&id_emb[(size_t)g * 128 + c];
    float4 g1 = *(const float4*)&id_emb[(size_t)g * 128 + c + 4];
    uint4 pg = make_uint4((uint)f2bf(g0.x) | ((uint)f2bf(g0.y) << 16),
                          (uint)f2bf(g0.z) | ((uint)f2bf(g0.w) << 16),
                          (uint)f2bf(g1.x) | ((uint)f2bf(g1.y) << 16),
                          (uint)f2bf(g1.z) | ((uint)f2bf(g1.w) << 16));
    *(uint4*)&gid[(size_t)row * 128 + c] = pg;
}

// ------- gather pass 1: z1 = A.xn_sc  (16-lane groups, unroll 4/2/1) -------
__global__ void k_agg1(const ushort* __restrict__ xn_sc, const int* __restrict__ rp,
                       const int* __restrict__ col, ushort* __restrict__ z1, int n) {
    int gtid = blockIdx.x * blockDim.x + threadIdx.x;
    int row  = gtid >> 4;
    int lane = gtid & 15;
    if (row >= n) return;
    int c = lane * 8;
    float a[8] = {0.f, 0.f, 0.f, 0.f, 0.f, 0.f, 0.f, 0.f};
    int e = rp[row], e1 = rp[row + 1];
    for (; e + 3 < e1; e += 4) {
        int s0 = col[e], s1 = col[e + 1], s2 = col[e + 2], s3 = col[e + 3];
        uint4 v0 = *(const uint4*)&xn_sc[(size_t)s0 * 128 + c];
        uint4 v1 = *(const uint4*)&xn_sc[(size_t)s1 * 128 + c];
        uint4 v2 = *(const uint4*)&xn_sc[(size_t)s2 * 128 + c];
        uint4 v3 = *(const uint4*)&xn_sc[(size_t)s3 * 128 + c];
        acc8(v0, a); acc8(v1, a); acc8(v2, a); acc8(v3, a);
    }
    if (e + 1 < e1) {
        int s0 = col[e], s1 = col[e + 1];
        uint4 v0 = *(const uint4*)&xn_sc[(size_t)s0 * 128 + c];
        uint4 v1 = *(const uint4*)&xn_sc[(size_t)s1 * 128 + c];
        acc8(v0, a); acc8(v1, a);
        e += 2;
    }
    if (e < e1) {
        uint4 v0 = *(const uint4*)&xn_sc[(size_t)col[e] * 128 + c];
        acc8(v0, a);
    }
    uint4 p = make_uint4((uint)f2bf(a[0]) | ((uint)f2bf(a[1]) << 16),
                         (uint)f2bf(a[2]) | ((uint)f2bf(a[3]) << 16),
                         (uint)f2bf(a[4]) | ((uint)f2bf(a[5]) << 16),
                         (uint)f2bf(a[6]) | ((uint)f2bf(a[7]) << 16));
    *(uint4*)&z1[(size_t)row * 128 + c] = p;
}

// --- gather pass 2 + conv2 epilogue (16-lane groups, unroll 4/2/1) ---
__global__ void k_agg2e(const ushort* __restrict__ q, const int* __restrict__ rp,
                        const int* __restrict__ col, const float* __restrict__ inrm,
                        const float* __restrict__ bias2, const ushort* __restrict__ gid,
                        float* __restrict__ out, int n) {
    int gtid = blockIdx.x * blockDim.x + threadIdx.x;
    int row  = gtid >> 4;
    int lane = gtid & 15;
    if (row >= n) return;
    int c = lane * 8;
    float a[8] = {0.f, 0.f, 0.f, 0.f, 0.f, 0.f, 0.f, 0.f};
    int e = rp[row], e1 = rp[row + 1];
    for (; e + 3 < e1; e += 4) {
        int s0 = col[e], s1 = col[e + 1], s2 = col[e + 2], s3 = col[e + 3];
        uint4 v0 = *(const uint4*)&q[(size_t)s0 * 128 + c];
        uint4 v1 = *(const uint4*)&q[(size_t)s1 * 128 + c];
        uint4 v2 = *(const uint4*)&q[(size_t)s2 * 128 + c];
        uint4 v3 = *(const uint4*)&q[(size_t)s3 * 128 + c];
        acc8(v0, a); acc8(v1, a); acc8(v2, a); acc8(v3, a);
    }
    if (e + 1 < e1) {
        int s0 = col[e], s1 = col[e + 1];
        uint4 v0 = *(const uint4*)&q[(size_t)s0 * 128 + c];
        uint4 v1 = *(const uint4*)&q[(size_t)s1 * 128 + c];
        acc8(v0, a); acc8(v1, a);
        e += 2;
    }
    if (e < e1) {
        uint4 v0 = *(const uint4*)&q[(size_t)col[e] * 128 + c];
        acc8(v0, a);
    }
    float win = inrm[row];
    float4 b0 = *(const float4*)&bias2[c];
    float4 b1 = *(const float4*)&bias2[c + 4];
    uint4 pg = *(const uint4*)&gid[(size_t)row * 128 + c];
    float4 o0, o1;
    o0.x = a[0] * win + b0.x + bf2f(pg.x & 0xffffu);
    o0.y = a[1] * win + b0.y + bf2f(pg.x >> 16);
    o0.z = a[2] * win + b0.z + bf2f(pg.y & 0xffffu);
    o0.w = a[3] * win + b0.w + bf2f(pg.y >> 16);
    o1.x = a[4] * win + b1.x + bf2f(pg.z & 0xffffu);
    o1.y = a[5] * win + b1.y + bf2f(pg.z >> 16);
    o1.z = a[6] * win + b1.z + bf2f(pg.w & 0xffffu);
    o1.w = a[7] * win + b1.w + bf2f(pg.w >> 16);
    *(float4*)&out[(size_t)row * 384 + 256 + c]     = o0;
    *(float4*)&out[(size_t)row * 384 + 256 + c + 4] = o1;
}

// ---- m97-style MFMA GEMM: 128 rows x 128 cols, BK=64, global_load_lds + XOR swizzle ----
// EPI==1 (conv1, grid.y=h): cols = W1T rows [h*128,h*128+128). Epilogue fuses conv1 output
//   and qin[:,128:384] (interleaved). EPI==3 (gemm_q): q = A @ W2 (bf16 out).
template<int K, int LDA, int EPI>
__global__ __launch_bounds__(256) void k_gemm(
    const ushort* __restrict__ A, const ushort* __restrict__ WT,
    const float* __restrict__ inrm, const float* __restrict__ onrm,
    const ushort* __restrict__ gid, const float* __restrict__ bias,
    ushort* __restrict__ xq, float* __restrict__ out, int n)
{
    __shared__ __align__(16) ushort As[128 * 64];
    __shared__ __align__(16) ushort Bs[128 * 64];
    int tid  = threadIdx.x;
    int lane = tid & 63;
    int w    = tid >> 6;
    int wm   = w >> 1, wn = w & 1;
    int lr   = lane & 15, lk = lane >> 4;
    int row0 = blockIdx.x * 128;
    int h    = blockIdx.y;
    int cb   = h * 128;

    const ushort* aSrc[4]; const ushort* bSrc[4]; int dOff[4];
    #pragma unroll
    for (int q = 0; q < 4; q++) {
        int g = w * 256 + q * 64 + lane;
        int row = g >> 3, lc = g & 7;
        int scol = ((lc ^ (row & 7)) << 3);
        aSrc[q] = A  + (size_t)(row0 + row) * LDA + scol;
        bSrc[q] = WT + (size_t)(cb + row) * K + scol;
        dOff[q] = (w * 256 + q * 64) * 8;
    }

    f32x4 acc[4][4];
    f32x4 zero = {0.f, 0.f, 0.f, 0.f};
    #pragma unroll
    for (int m = 0; m < 4; m++)
        #pragma unroll
        for (int nn = 0; nn < 4; nn++) acc[m][nn] = zero;

    int sw = (lr & 7);
    const char* ab = (const char*)As;
    const char* bb = (const char*)Bs;

    for (int ks = 0; ks < K / 64; ks++) {
        int k0 = ks * 64;
        #pragma unroll
        for (int q = 0; q < 4; q++) {
            stage16(aSrc[q] + k0, As + dOff[q]);
            stage16(bSrc[q] + k0, Bs + dOff[q]);
        }
        __syncthreads();
        #pragma unroll
        for (int kk = 0; kk < 2; kk++) {
            bf16x8 af[4], bf[4];
            #pragma unroll
            for (int m = 0; m < 4; m++) {
                int row = wm * 64 + m * 16 + lr;
                af[m] = *(const bf16x8*)(ab + row * 128 + (((kk * 4 + lk) ^ sw) << 4));
            }
            #pragma unroll
            for (int nn = 0; nn < 4; nn++) {
                int brow = (EPI == 1)
                    ? ((nn & 2) ? 64 : 0) + wn * 32 + (nn & 1) * 16 + lr
                    : wn * 64 + nn * 16 + lr;
                bf[nn] = *(const bf16x8*)(bb + brow * 128 + (((kk * 4 + lk) ^ sw) << 4));
            }
            #pragma unroll
            for (int m = 0; m < 4; m++)
                #pragma unroll
                for (int nn = 0; nn < 4; nn++)
                    acc[m][nn] = __builtin_amdgcn_mfma_f32_16x16x32_bf16(af[m], bf[nn], acc[m][nn], 0, 0, 0);
        }
        __syncthreads();
    }

    #pragma unroll
    for (int m = 0; m < 4; m++) {
        int rb = row0 + wm * 64 + m * 16 + lk * 4;
        if (EPI == 1) {
            #pragma unroll
            for (int nn = 0; nn < 2; nn++) {
                int po = wn * 32 + nn * 16 + lr;
                int cv = h * 64 + po;
                float biv = bias[h * 128 + po];
                float bit = bias[h * 128 + 64 + po];
                #pragma unroll
                for (int j = 0; j < 4; j++) {
                    int r = rb + j;
                    if (r >= n) continue;
                    float win = inrm[r];
                    float won = onrm[r];
                    float ge = bf2f((uint)gid[(size_t)r * 128 + cv]);
                    float tv = acc[m][nn][j] * win + biv + ge;
                    float tt = acc[m][nn + 2][j] * win + bit + ge;
                    float lv = lrelu(tv), lt = lrelu(tt);
                    out[(size_t)r * 384 + 128 + cv] = 0.5f * (lv + lt);
                    uint pk = (uint)f2bf(lv * won) | ((uint)f2bf(lt * won) << 16);
                    *(uint*)&xq[(size_t)r * 384 + 128 + 2 * cv] = pk;
                }
            }
        } else {
            #pragma unroll
            for (int nn = 0; nn < 4; nn++) {
                int cg = wn * 64 + nn * 16 + lr;
                #pragma unroll
                for (int j = 0; j < 4; j++) {
                    int r = rb + j;
                    if (r >= n) continue;
                    xq[(size_t)r * 128 + cg] = f2bf(acc[m][nn][j]);
                }
            }
        }
    }
}

extern "C" void kernel_launch(void* const* d_in, const int* in_sizes, int n_in,
                              void* d_out, int out_size, void* d_ws, size_t ws_size,
                              hipStream_t stream) {
    const float* x      = (const float*)d_in[0];
    const float* id_emb = (const float*)d_in[1];
    const float* Wv0    = (const float*)d_in[2];
    const float* bv0    = (const float*)d_in[3];
    const float* Wv1    = (const float*)d_in[4];
    const float* bv1    = (const float*)d_in[5];
    const float* Wt0    = (const float*)d_in[6];
    const float* bt0    = (const float*)d_in[7];
    const float* Wt1    = (const float*)d_in[8];
    const float* bt1    = (const float*)d_in[9];
    const int*   src    = (const int*)d_in[10];
    const int*   dst    = (const int*)d_in[11];
    const int*   dsti   = (const int*)d_in[12];
    const int E = in_sizes[10];
    const int N = in_sizes[12];
    float* out = (float*)d_out;

    char* p = (char*)d_ws;
    ushort* xn_sc   = (ushort*)p; p += (size_t)N * 128 * 2;
    ushort* qin     = (ushort*)p; p += (size_t)N * 384 * 2;   // [lxn | xhat interleaved]
    ushort* z1      = (ushort*)p; p += (size_t)N * 128 * 2;
    ushort* q       = (ushort*)p; p += (size_t)N * 128 * 2;
    ushort* gid     = (ushort*)p; p += (size_t)N * 128 * 2;
    ushort* W1T     = (ushort*)p; p += 256 * 128 * 2;
    ushort* W2T     = (ushort*)p; p += 128 * 384 * 2;
    float* bias_cat = (float*)p;  p += 256 * 4;
    float* bias2    = (float*)p;  p += 128 * 4;
    float* onrm     = (float*)p;  p += (size_t)N * 4;
    float* inrm     = (float*)p;  p += (size_t)N * 4;
    int* deg_out    = (int*)p;    p += (size_t)N * 4;
    int* deg_in     = (int*)p;    p += (size_t)N * 4;
    int* cursor     = (int*)p;    p += (size_t)N * 4;
    int* row_ptr    = (int*)p;    p += (size_t)(N + 1) * 4;
    int* csum       = (int*)p;    p += 1024 * 4;
    int* col        = (int*)p;    p += (size_t)E * 4;

    hipMemsetAsync(deg_out, 0, (size_t)N * 2 * 4, stream);   // deg_out|deg_in contiguous

    int be = (E + 255) / 256;
    int bn = (N + 255) / 256;
    int bq = (N * 16 + 255) / 256;          // 16-lane groups (normx + gathers)
    int bg = (N + 127) / 128;               // 128-row GEMM tiles
    int nb = (N + 1023) / 1024;             // scan chunks

    k_degrees<<<be, 256, 0, stream>>>(src, dst, deg_out, deg_in, E);
    k_scan1  <<<nb, 1024, 0, stream>>>(deg_out, deg_in, row_ptr, csum, onrm, inrm, N);
    k_scan2  <<<1, 1024, 0, stream>>>(csum, nb);
    k_scan3  <<<bn, 256, 0, stream>>>(row_ptr, csum, cursor, N);
    k_fill   <<<be, 256, 0, stream>>>(src, dst, cursor, col, E);
    k_wprep  <<<192, 256, 0, stream>>>(Wv0, Wt0, Wv1, Wt1, bv0, bt0, bv1, bt1,
                                       W1T, W2T, bias_cat, bias2);
    k_normx  <<<bq, 256, 0, stream>>>(x, onrm, dsti, id_emb, xn_sc, qin, gid, out, N);

    k_agg1<<<bq, 256, 0, stream>>>(xn_sc, row_ptr, col, z1, N);
    k_gemm<128, 128, 1><<<dim3(bg, 2), 256, 0, stream>>>(
        z1, W1T, inrm, onrm, gid, bias_cat, qin, out, N);
    k_gemm<384, 384, 3><<<dim3(bg, 1), 256, 0, stream>>>(
        qin, W2T, inrm, onrm, gid, bias2, q, out, N);
    k_agg2e<<<bq, 256, 0, stream>>>(q, row_ptr, col, inrm, bias2, gid, out, N);
}

// Round 14
// 262.709 us; speedup vs baseline: 1.5440x; 1.0950x over previous
//
#include <hip/hip_runtime.h>
#include <math.h>

// MMGCN: both GEMMs pushed through the (linear) aggregations, and FUSED into one kernel:
//   z1 = A.(xn*onrm)                       -> agg1 (16-lane groups)
//   k_conv (per 64-row block):
//     phase 1: conv1 = z1 @ W1T (K=128, N=256 v/t-paired)  -> out[:,128:256] +
//              xhat tile (bf16, interleaved) -> LDS Qs (XOR-swizzled), NEVER global
//     phase 2: q = [qin0 | Qs] @ W2 (K=384) -> q[N][128] bf16
//   out[:,256:384] = agg(q)*in_norm + 0.5(b1v+b1t) + gid  -> agg2e
// GEMM staging: global_load_lds (16B DMA), linear LDS dest + pre-swizzled source (rule #21).
// Qs hand-off: byte ^= ((row&7)<<4) on BOTH ds_write and ds_read sides.

typedef unsigned int uint;
typedef unsigned short ushort;
using bf16x8 = __attribute__((ext_vector_type(8))) short;
using f32x4  = __attribute__((ext_vector_type(4))) float;

__device__ __forceinline__ float lrelu(float v) { return v >= 0.0f ? v : 0.01f * v; }
__device__ __forceinline__ float bf2f(uint us) { return __uint_as_float(us << 16); }
__device__ __forceinline__ ushort f2bf(float f) {
    uint u = __float_as_uint(f);
    u += 0x7fffu + ((u >> 16) & 1u);   // round-to-nearest-even
    return (ushort)(u >> 16);
}
__device__ __forceinline__ void stage16(const ushort* g, ushort* l) {
    __builtin_amdgcn_global_load_lds(
        (const __attribute__((address_space(1))) void*)(g),
        (__attribute__((address_space(3))) void*)(l), 16, 0, 0);
}
__device__ __forceinline__ void acc8(uint4 v, float* a) {
    a[0] += bf2f(v.x & 0xffffu); a[1] += bf2f(v.x >> 16);
    a[2] += bf2f(v.y & 0xffffu); a[3] += bf2f(v.y >> 16);
    a[4] += bf2f(v.z & 0xffffu); a[5] += bf2f(v.z >> 16);
    a[6] += bf2f(v.w & 0xffffu); a[7] += bf2f(v.w >> 16);
}

// ---------------- degree histograms ----------------
__global__ void k_degrees(const int* __restrict__ src, const int* __restrict__ dst,
                          int* __restrict__ deg_out, int* __restrict__ deg_in, int E) {
    int e = blockIdx.x * blockDim.x + threadIdx.x;
    if (e < E) {
        atomicAdd(&deg_out[src[e]], 1);
        atomicAdd(&deg_in[dst[e]], 1);
    }
}

// ---------------- scan1 (+ norms fused): per-1024-chunk inclusive scan of deg_in ------
__global__ void k_scan1(const int* __restrict__ deg_out, const int* __restrict__ deg_in,
                        int* __restrict__ row_ptr, int* __restrict__ csum,
                        float* __restrict__ onrm, float* __restrict__ inrm, int n) {
    __shared__ int wsum[16];
    __shared__ int wpre[16];
    int lane = threadIdx.x & 63;
    int wid  = threadIdx.x >> 6;
    int i = blockIdx.x * 1024 + threadIdx.x;
    int v = (i < n) ? deg_in[i] : 0;
    if (i < n) {
        onrm[i] = 1.0f / sqrtf((float)max(deg_out[i], 1));
        inrm[i] = 1.0f / sqrtf((float)max(v, 1));
    }
    int s = v;
    #pragma unroll
    for (int off = 1; off < 64; off <<= 1) {
        int t = __shfl_up(s, off, 64);
        if (lane >= off) s += t;
    }
    if (lane == 63) wsum[wid] = s;
    __syncthreads();
    if (wid == 0) {
        int wv = (lane < 16) ? wsum[lane] : 0;
        int ss = wv;
        #pragma unroll
        for (int off = 1; off < 16; off <<= 1) {
            int t = __shfl_up(ss, off, 64);
            if (lane >= off) ss += t;
        }
        if (lane < 16) wpre[lane] = ss - wv;
    }
    __syncthreads();
    int incl = s + wpre[wid];
    if (i < n) row_ptr[i + 1] = incl;                        // chunk-local for now
    if (threadIdx.x == 1023) csum[blockIdx.x] = incl;        // chunk total
}

__global__ void k_scan2(int* __restrict__ csum, int nb) {
    __shared__ int wsum[16];
    __shared__ int wpre[16];
    int lane = threadIdx.x & 63;
    int wid  = threadIdx.x >> 6;
    int i = threadIdx.x;
    int v = (i < nb) ? csum[i] : 0;
    int s = v;
    #pragma unroll
    for (int off = 1; off < 64; off <<= 1) {
        int t = __shfl_up(s, off, 64);
        if (lane >= off) s += t;
    }
    if (lane == 63) wsum[wid] = s;
    __syncthreads();
    if (wid == 0) {
        int wv = (lane < 16) ? wsum[lane] : 0;
        int ss = wv;
        #pragma unroll
        for (int off = 1; off < 16; off <<= 1) {
            int t = __shfl_up(ss, off, 64);
            if (lane >= off) ss += t;
        }
        if (lane < 16) wpre[lane] = ss - wv;
    }
    __syncthreads();
    if (i < nb) csum[i] = s + wpre[wid];
}

// scan3: finalize row_ptr and materialize cursor = row_ptr (absolute fill cursors)
__global__ void k_scan3(int* __restrict__ row_ptr, const int* __restrict__ csum,
                        int* __restrict__ cursor, int n) {
    int i = blockIdx.x * blockDim.x + threadIdx.x;
    if (i == 0) { row_ptr[0] = 0; cursor[0] = 0; }
    if (i < n) {
        int b = i >> 10;
        int rv = row_ptr[i + 1] + ((b > 0) ? csum[b - 1] : 0);
        row_ptr[i + 1] = rv;
        if (i + 1 < n) cursor[i + 1] = rv;
    }
}

__global__ void k_fill(const int* __restrict__ src, const int* __restrict__ dst,
                       int* __restrict__ cursor, int* __restrict__ col, int E) {
    int e = blockIdx.x * blockDim.x + threadIdx.x;
    if (e < E) {
        int pos = atomicAdd(&cursor[dst[e]], 1);
        col[pos] = src[e];
    }
}

// ---------------- weight prep ----------------
// W1T [256 rows][128 k]: row h*128+p: p<64 -> Wv0 col (h*64+p); p>=64 -> Wt0 col (h*64+p-64)
// W2T [128 rows][384 k]: k 0:128 = 0.5(Wv1+Wt1); k 128+2q+b = 0.5 Wb1[128+q]  (interleaved)
__global__ void k_wprep(const float* __restrict__ Wv0, const float* __restrict__ Wt0,
                        const float* __restrict__ Wv1, const float* __restrict__ Wt1,
                        const float* __restrict__ bv0, const float* __restrict__ bt0,
                        const float* __restrict__ bv1, const float* __restrict__ bt1,
                        ushort* __restrict__ W1T, ushort* __restrict__ W2T,
                        float* __restrict__ bias_cat, float* __restrict__ bias2) {
    int t = blockIdx.x * blockDim.x + threadIdx.x;
    if (t < 256 * 128) {
        int cp = t >> 7, k = t & 127;
        int p = cp & 127;
        int col = ((cp >> 7) << 6) + (p & 63);
        float v = (p < 64) ? Wv0[k * 128 + col] : Wt0[k * 128 + col];
        W1T[cp * 128 + k] = f2bf(v);
    }
    if (t < 128 * 384) {
        int c = t / 384, r = t % 384;
        float v;
        if (r < 128) v = 0.5f * (Wv1[r * 128 + c] + Wt1[r * 128 + c]);
        else {
            int q = (r - 128) >> 1;
            v = 0.5f * (((r - 128) & 1) ? Wt1[(128 + q) * 128 + c] : Wv1[(128 + q) * 128 + c]);
        }
        W2T[c * 384 + r] = f2bf(v);
    }
    if (t < 256) {
        int p = t & 127;
        int col = ((t >> 7) << 6) + (p & 63);
        bias_cat[t] = (p < 64) ? bv0[col] : bt0[col];
    }
    if (t < 128) bias2[t] = 0.5f * (bv1[t] + bt1[t]);
}

// --- row L2-normalize x (16-lane groups); out[:,0:128]=leaky(xn); xn_sc=xn*onrm;
//     qin0 = leaky(xn_sc) [N][128]; gid = id_emb[dst_ids] densified (bf16) ---
__global__ void k_normx(const float* __restrict__ x, const float* __restrict__ onrm,
                        const int* __restrict__ dsti, const float* __restrict__ id_emb,
                        ushort* __restrict__ xn_sc, ushort* __restrict__ qin0,
                        ushort* __restrict__ gid, float* __restrict__ out, int n) {
    int gtid = blockIdx.x * blockDim.x + threadIdx.x;
    int row  = gtid >> 4;
    int lane = gtid & 15;
    if (row >= n) return;
    int c = lane * 8;
    float4 v0 = *(const float4*)&x[(size_t)row * 128 + c];
    float4 v1 = *(const float4*)&x[(size_t)row * 128 + c + 4];
    float s = v0.x * v0.x + v0.y * v0.y + v0.z * v0.z + v0.w * v0.w
            + v1.x * v1.x + v1.y * v1.y + v1.z * v1.z + v1.w * v1.w;
    #pragma unroll
    for (int off = 1; off < 16; off <<= 1) s += __shfl_xor(s, off, 64);
    float scale = 1.0f / fmaxf(sqrtf(s), 1e-12f);
    float nx[8] = {v0.x * scale, v0.y * scale, v0.z * scale, v0.w * scale,
                   v1.x * scale, v1.y * scale, v1.z * scale, v1.w * scale};
    *(float4*)&out[(size_t)row * 384 + c] =
        make_float4(lrelu(nx[0]), lrelu(nx[1]), lrelu(nx[2]), lrelu(nx[3]));
    *(float4*)&out[(size_t)row * 384 + c + 4] =
        make_float4(lrelu(nx[4]), lrelu(nx[5]), lrelu(nx[6]), lrelu(nx[7]));
    float so = onrm[row];
    float sx[8];
    #pragma unroll
    for (int j = 0; j < 8; j++) sx[j] = nx[j] * so;
    uint4 px = make_uint4((uint)f2bf(sx[0]) | ((uint)f2bf(sx[1]) << 16),
                          (uint)f2bf(sx[2]) | ((uint)f2bf(sx[3]) << 16),
                          (uint)f2bf(sx[4]) | ((uint)f2bf(sx[5]) << 16),
                          (uint)f2bf(sx[6]) | ((uint)f2bf(sx[7]) << 16));
    *(uint4*)&xn_sc[(size_t)row * 128 + c] = px;
    uint4 pq = make_uint4((uint)f2bf(lrelu(sx[0])) | ((uint)f2bf(lrelu(sx[1])) << 16),
                          (uint)f2bf(lrelu(sx[2])) | ((uint)f2bf(lrelu(sx[3])) << 16),
                          (uint)f2bf(lrelu(sx[4])) | ((uint)f2bf(lrelu(sx[5])) << 16),
                          (uint)f2bf(lrelu(sx[6])) | ((uint)f2bf(lrelu(sx[7])) << 16));
    *(uint4*)&qin0[(size_t)row * 128 + c] = pq;
    int g = dsti[row];
    float4 g0 = *(const float4*)&id_emb[(size_t)g * 128 + c];
    float4 g1 = *(const float4*)&id_emb[(size_t)g * 128 + c + 4];
    uint4 pg = make_uint4((uint)f2bf(g0.x) | ((uint)f2bf(g0.y) << 16),
                          (uint)f2bf(g0.z) | ((uint)f2bf(g0.w) << 16),
                          (uint)f2bf(g1.x) | ((uint)f2bf(g1.y) << 16),
                          (uint)f2bf(g1.z) | ((uint)f2bf(g1.w) << 16));
    *(uint4*)&gid[(size_t)row * 128 + c] = pg;
}

// ------- gather pass 1: z1 = A.xn_sc  (16-lane groups, unroll 4/2/1) -------
__global__ void k_agg1(const ushort* __restrict__ xn_sc, const int* __restrict__ rp,
                       const int* __restrict__ col, ushort* __restrict__ z1, int n) {
    int gtid = blockIdx.x * blockDim.x + threadIdx.x;
    int row  = gtid >> 4;
    int lane = gtid & 15;
    if (row >= n) return;
    int c = lane * 8;
    float a[8] = {0.f, 0.f, 0.f, 0.f, 0.f, 0.f, 0.f, 0.f};
    int e = rp[row], e1 = rp[row + 1];
    for (; e + 3 < e1; e += 4) {
        int s0 = col[e], s1 = col[e + 1], s2 = col[e + 2], s3 = col[e + 3];
        uint4 v0 = *(const uint4*)&xn_sc[(size_t)s0 * 128 + c];
        uint4 v1 = *(const uint4*)&xn_sc[(size_t)s1 * 128 + c];
        uint4 v2 = *(const uint4*)&xn_sc[(size_t)s2 * 128 + c];
        uint4 v3 = *(const uint4*)&xn_sc[(size_t)s3 * 128 + c];
        acc8(v0, a); acc8(v1, a); acc8(v2, a); acc8(v3, a);
    }
    if (e + 1 < e1) {
        int s0 = col[e], s1 = col[e + 1];
        uint4 v0 = *(const uint4*)&xn_sc[(size_t)s0 * 128 + c];
        uint4 v1 = *(const uint4*)&xn_sc[(size_t)s1 * 128 + c];
        acc8(v0, a); acc8(v1, a);
        e += 2;
    }
    if (e < e1) {
        uint4 v0 = *(const uint4*)&xn_sc[(size_t)col[e] * 128 + c];
        acc8(v0, a);
    }
    uint4 p = make_uint4((uint)f2bf(a[0]) | ((uint)f2bf(a[1]) << 16),
                         (uint)f2bf(a[2]) | ((uint)f2bf(a[3]) << 16),
                         (uint)f2bf(a[4]) | ((uint)f2bf(a[5]) << 16),
                         (uint)f2bf(a[6]) | ((uint)f2bf(a[7]) << 16));
    *(uint4*)&z1[(size_t)row * 128 + c] = p;
}

// --- gather pass 2 + conv2 epilogue (16-lane groups, unroll 4/2/1) ---
__global__ void k_agg2e(const ushort* __restrict__ q, const int* __restrict__ rp,
                        const int* __restrict__ col, const float* __restrict__ inrm,
                        const float* __restrict__ bias2, const ushort* __restrict__ gid,
                        float* __restrict__ out, int n) {
    int gtid = blockIdx.x * blockDim.x + threadIdx.x;
    int row  = gtid >> 4;
    int lane = gtid & 15;
    if (row >= n) return;
    int c = lane * 8;
    float a[8] = {0.f, 0.f, 0.f, 0.f, 0.f, 0.f, 0.f, 0.f};
    int e = rp[row], e1 = rp[row + 1];
    for (; e + 3 < e1; e += 4) {
        int s0 = col[e], s1 = col[e + 1], s2 = col[e + 2], s3 = col[e + 3];
        uint4 v0 = *(const uint4*)&q[(size_t)s0 * 128 + c];
        uint4 v1 = *(const uint4*)&q[(size_t)s1 * 128 + c];
        uint4 v2 = *(const uint4*)&q[(size_t)s2 * 128 + c];
        uint4 v3 = *(const uint4*)&q[(size_t)s3 * 128 + c];
        acc8(v0, a); acc8(v1, a); acc8(v2, a); acc8(v3, a);
    }
    if (e + 1 < e1) {
        int s0 = col[e], s1 = col[e + 1];
        uint4 v0 = *(const uint4*)&q[(size_t)s0 * 128 + c];
        uint4 v1 = *(const uint4*)&q[(size_t)s1 * 128 + c];
        acc8(v0, a); acc8(v1, a);
        e += 2;
    }
    if (e < e1) {
        uint4 v0 = *(const uint4*)&q[(size_t)col[e] * 128 + c];
        acc8(v0, a);
    }
    float win = inrm[row];
    float4 b0 = *(const float4*)&bias2[c];
    float4 b1 = *(const float4*)&bias2[c + 4];
    uint4 pg = *(const uint4*)&gid[(size_t)row * 128 + c];
    float4 o0, o1;
    o0.x = a[0] * win + b0.x + bf2f(pg.x & 0xffffu);
    o0.y = a[1] * win + b0.y + bf2f(pg.x >> 16);
    o0.z = a[2] * win + b0.z + bf2f(pg.y & 0xffffu);
    o0.w = a[3] * win + b0.w + bf2f(pg.y >> 16);
    o1.x = a[4] * win + b1.x + bf2f(pg.z & 0xffffu);
    o1.y = a[5] * win + b1.y + bf2f(pg.z >> 16);
    o1.z = a[6] * win + b1.z + bf2f(pg.w & 0xffffu);
    o1.w = a[7] * win + b1.w + bf2f(pg.w >> 16);
    *(float4*)&out[(size_t)row * 384 + 256 + c]     = o0;
    *(float4*)&out[(size_t)row * 384 + 256 + c + 4] = o1;
}

// ---- fused conv kernel: 64 rows/block, 512 threads (8 waves, 2x4) ----
// Phase 1: conv1 (K=128, N=256 paired) from z1/W1T; epilogue -> out[:,128:256] + Qs (LDS).
// Phase 2: q = [qin0 | Qs] @ W2 (K=384, N=128), W2 double-buffered; q bf16 out.
__global__ __launch_bounds__(512) void k_conv(
    const ushort* __restrict__ z1, const ushort* __restrict__ W1T,
    const ushort* __restrict__ qin0, const ushort* __restrict__ W2T,
    const float* __restrict__ inrm, const float* __restrict__ onrm,
    const ushort* __restrict__ gid, const float* __restrict__ bias_cat,
    ushort* __restrict__ q, float* __restrict__ out, int n)
{
    __shared__ __align__(16) ushort As[2 * 64 * 64];   // 16KB: A tiles (2 halves)
    __shared__ __align__(16) ushort Bs[256 * 64];      // 32KB: p1 full W1T step; p2 2x16KB halves
    __shared__ __align__(16) ushort Qs[64 * 256];      // 32KB: qin cols 128:384, swizzled
    int tid  = threadIdx.x;
    int lane = tid & 63;
    int w    = tid >> 6;            // 0..7
    int wm   = w >> 2, wn = w & 3;
    int lr   = lane & 15, lk = lane >> 4;
    int row0 = blockIdx.x * 64;
    int sw   = lr & 7;
    int h    = wn >> 1;             // phase-1 pair geometry
    int pbase = (wn & 1) * 32;

    // A-staging granule for this thread (64x64 tile = 512 granules, 1/thread)
    int gA = w * 64 + lane;
    int rA = gA >> 3, lcA = gA & 7;
    int scolA = ((lcA ^ (rA & 7)) << 3);
    int dA = gA * 8;

    // ---------------- phase 1: conv1 ----------------
    f32x4 acc[2][4];
    f32x4 zero = {0.f, 0.f, 0.f, 0.f};
    #pragma unroll
    for (int m = 0; m < 2; m++)
        #pragma unroll
        for (int nn = 0; nn < 4; nn++) acc[m][nn] = zero;

    const ushort* aSrc1 = z1 + (size_t)(row0 + rA) * 128 + scolA;
    for (int ks = 0; ks < 2; ks++) {
        stage16(aSrc1 + ks * 64, As + ks * 4096 + dA);
        #pragma unroll
        for (int c = 0; c < 4; c++) {
            int gB = w * 256 + c * 64 + lane;
            int rB = gB >> 3, lcB = gB & 7;
            stage16(W1T + (size_t)rB * 128 + ks * 64 + ((lcB ^ (rB & 7)) << 3), Bs + gB * 8);
        }
        __syncthreads();
        const char* ab = (const char*)(As + ks * 4096);
        const char* bb = (const char*)Bs;
        #pragma unroll
        for (int kk = 0; kk < 2; kk++) {
            int kx = (((kk * 4 + lk) ^ sw) << 4);
            bf16x8 af[2], bf[4];
            #pragma unroll
            for (int m = 0; m < 2; m++) {
                int r = wm * 32 + m * 16 + lr;
                af[m] = *(const bf16x8*)(ab + r * 128 + kx);
            }
            #pragma unroll
            for (int nn = 0; nn < 2; nn++) {
                int vrow = h * 128 + pbase + nn * 16 + lr;
                bf[nn]     = *(const bf16x8*)(bb + vrow * 128 + kx);
                bf[nn + 2] = *(const bf16x8*)(bb + (vrow + 64) * 128 + kx);
            }
            #pragma unroll
            for (int m = 0; m < 2; m++)
                #pragma unroll
                for (int nn = 0; nn < 4; nn++)
                    acc[m][nn] = __builtin_amdgcn_mfma_f32_16x16x32_bf16(af[m], bf[nn], acc[m][nn], 0, 0, 0);
        }
        __syncthreads();
    }

    // ---------------- phase-1 epilogue: out[:,128:256] + Qs (swizzled LDS) ----------------
    #pragma unroll
    for (int m = 0; m < 2; m++) {
        int rloc0 = wm * 32 + m * 16 + lk * 4;
        #pragma unroll
        for (int nn = 0; nn < 2; nn++) {
            int po = pbase + nn * 16 + lr;
            int cv = h * 64 + po;                 // pair/v-col 0..127
            float biv = bias_cat[h * 128 + po];
            float bit = bias_cat[h * 128 + 64 + po];
            #pragma unroll
            for (int j = 0; j < 4; j++) {
                int rl = rloc0 + j;
                int r  = row0 + rl;
                float lv = 0.f, lt = 0.f;
                if (r < n) {
                    float win = inrm[r];
                    float won = onrm[r];
                    float ge = bf2f((uint)gid[(size_t)r * 128 + cv]);
                    float tv = acc[m][nn][j] * win + biv + ge;
                    float tt = acc[m][nn + 2][j] * win + bit + ge;
                    lv = lrelu(tv); lt = lrelu(tt);
                    out[(size_t)r * 384 + 128 + cv] = 0.5f * (lv + lt);
                    lv *= won; lt *= won;
                }
                uint pk = (uint)f2bf(lv) | ((uint)f2bf(lt) << 16);
                *(uint*)((char*)Qs + ((rl * 512 + 4 * cv) ^ ((rl & 7) << 4))) = pk;
            }
        }
    }
    // prestage phase 2: qin0 k-steps 0,1 into As halves; W2T step 0 into Bs half0
    const ushort* aSrc0 = qin0 + (size_t)(row0 + rA) * 128 + scolA;
    stage16(aSrc0,      As + dA);
    stage16(aSrc0 + 64, As + 4096 + dA);
    #pragma unroll
    for (int c = 0; c < 2; c++) {
        int g2 = w * 128 + c * 64 + lane;
        int r2 = g2 >> 3, lc2 = g2 & 7;
        stage16(W2T + (size_t)r2 * 384 + ((lc2 ^ (r2 & 7)) << 3), Bs + g2 * 8);
    }
    __syncthreads();   // Qs ds_writes + DMA staged all visible

    // ---------------- phase 2: q = [qin0 | Qs] @ W2, K=384 ----------------
    f32x4 acc2[2][2];
    #pragma unroll
    for (int m = 0; m < 2; m++)
        #pragma unroll
        for (int nn = 0; nn < 2; nn++) acc2[m][nn] = zero;

    for (int s = 0; s < 6; s++) {
        if (s < 5) {                              // stage next W2 k-step into other half
            int nh = (s + 1) & 1;
            #pragma unroll
            for (int c = 0; c < 2; c++) {
                int g2 = w * 128 + c * 64 + lane;
                int r2 = g2 >> 3, lc2 = g2 & 7;
                stage16(W2T + (size_t)r2 * 384 + (s + 1) * 64 + ((lc2 ^ (r2 & 7)) << 3),
                        Bs + nh * 8192 + g2 * 8);
            }
        }
        const char* bb2 = (const char*)(Bs + (s & 1) * 8192);
        #pragma unroll
        for (int kk = 0; kk < 2; kk++) {
            int kx = (((kk * 4 + lk) ^ sw) << 4);
            bf16x8 af[2], bf[2];
            #pragma unroll
            for (int m = 0; m < 2; m++) {
                int rl = wm * 32 + m * 16 + lr;
                if (s < 2)
                    af[m] = *(const bf16x8*)((const char*)(As + s * 4096) + rl * 128 + kx);
                else
                    af[m] = *(const bf16x8*)((const char*)Qs +
                              ((rl * 512 + (s - 2) * 128 + (kk * 4 + lk) * 16) ^ ((rl & 7) << 4)));
            }
            #pragma unroll
            for (int nn = 0; nn < 2; nn++) {
                int cg = wn * 32 + nn * 16 + lr;
                bf[nn] = *(const bf16x8*)(bb2 + cg * 128 + kx);
            }
            #pragma unroll
            for (int m = 0; m < 2; m++)
                #pragma unroll
                for (int nn = 0; nn < 2; nn++)
                    acc2[m][nn] = __builtin_amdgcn_mfma_f32_16x16x32_bf16(af[m], bf[nn], acc2[m][nn], 0, 0, 0);
        }
        __syncthreads();   // next-step staging visible; this step's Bs reads done
    }

    // ---------------- phase-2 epilogue: q (bf16) ----------------
    #pragma unroll
    for (int m = 0; m < 2; m++) {
        int rb = row0 + wm * 32 + m * 16 + lk * 4;
        #pragma unroll
        for (int nn = 0; nn < 2; nn++) {
            int cg = wn * 32 + nn * 16 + lr;
            #pragma unroll
            for (int j = 0; j < 4; j++) {
                int r = rb + j;
                if (r < n) q[(size_t)r * 128 + cg] = f2bf(acc2[m][nn][j]);
            }
        }
    }
}

extern "C" void kernel_launch(void* const* d_in, const int* in_sizes, int n_in,
                              void* d_out, int out_size, void* d_ws, size_t ws_size,
                              hipStream_t stream) {
    const float* x      = (const float*)d_in[0];
    const float* id_emb = (const float*)d_in[1];
    const float* Wv0    = (const float*)d_in[2];
    const float* bv0    = (const float*)d_in[3];
    const float* Wv1    = (const float*)d_in[4];
    const float* bv1    = (const float*)d_in[5];
    const float* Wt0    = (const float*)d_in[6];
    const float* bt0    = (const float*)d_in[7];
    const float* Wt1    = (const float*)d_in[8];
    const float* bt1    = (const float*)d_in[9];
    const int*   src    = (const int*)d_in[10];
    const int*   dst    = (const int*)d_in[11];
    const int*   dsti   = (const int*)d_in[12];
    const int E = in_sizes[10];
    const int N = in_sizes[12];
    float* out = (float*)d_out;

    char* p = (char*)d_ws;
    ushort* xn_sc   = (ushort*)p; p += (size_t)N * 128 * 2;
    ushort* qin0    = (ushort*)p; p += (size_t)N * 128 * 2;
    ushort* z1      = (ushort*)p; p += (size_t)N * 128 * 2;
    ushort* q       = (ushort*)p; p += (size_t)N * 128 * 2;
    ushort* gid     = (ushort*)p; p += (size_t)N * 128 * 2;
    ushort* W1T     = (ushort*)p; p += 256 * 128 * 2;
    ushort* W2T     = (ushort*)p; p += 128 * 384 * 2;
    float* bias_cat = (float*)p;  p += 256 * 4;
    float* bias2    = (float*)p;  p += 128 * 4;
    float* onrm     = (float*)p;  p += (size_t)N * 4;
    float* inrm     = (float*)p;  p += (size_t)N * 4;
    int* deg_out    = (int*)p;    p += (size_t)N * 4;
    int* deg_in     = (int*)p;    p += (size_t)N * 4;
    int* cursor     = (int*)p;    p += (size_t)N * 4;
    int* row_ptr    = (int*)p;    p += (size_t)(N + 1) * 4;
    int* csum       = (int*)p;    p += 1024 * 4;
    int* col        = (int*)p;    p += (size_t)E * 4;

    hipMemsetAsync(deg_out, 0, (size_t)N * 2 * 4, stream);   // deg_out|deg_in contiguous

    int be = (E + 255) / 256;
    int bn = (N + 255) / 256;
    int bq = (N * 16 + 255) / 256;          // 16-lane groups (normx + gathers)
    int bc = (N + 63) / 64;                 // 64-row fused-conv tiles
    int nb = (N + 1023) / 1024;             // scan chunks

    k_degrees<<<be, 256, 0, stream>>>(src, dst, deg_out, deg_in, E);
    k_scan1  <<<nb, 1024, 0, stream>>>(deg_out, deg_in, row_ptr, csum, onrm, inrm, N);
    k_scan2  <<<1, 1024, 0, stream>>>(csum, nb);
    k_scan3  <<<bn, 256, 0, stream>>>(row_ptr, csum, cursor, N);
    k_fill   <<<be, 256, 0, stream>>>(src, dst, cursor, col, E);
    k_wprep  <<<192, 256, 0, stream>>>(Wv0, Wt0, Wv1, Wt1, bv0, bt0, bv1, bt1,
                                       W1T, W2T, bias_cat, bias2);
    k_normx  <<<bq, 256, 0, stream>>>(x, onrm, dsti, id_emb, xn_sc, qin0, gid, out, N);

    k_agg1 <<<bq, 256, 0, stream>>>(xn_sc, row_ptr, col, z1, N);
    k_conv <<<bc, 512, 0, stream>>>(z1, W1T, qin0, W2T, inrm, onrm, gid,
                                    bias_cat, q, out, N);
    k_agg2e<<<bq, 256, 0, stream>>>(q, row_ptr, col, inrm, bias2, gid, out, N);
}